// Round 1
// baseline (808.935 us; speedup 1.0000x reference)
//
#include <hip/hip_runtime.h>
#include <math.h>

#define NB 8
#define NC 512
#define NHW 1024
#define NG 32
#define CPG 16
#define QKV_C 1536
#define EPS 1e-5f

// ---------------- GroupNorm statistics: one block per (b,g) group ----------------
// group data is contiguous: 16 channels * 1024 spatial = 16384 floats
__global__ __launch_bounds__(256) void gn_stats_k(const float* __restrict__ x,
                                                  float* __restrict__ mu,
                                                  float* __restrict__ rinv) {
    const int grp = blockIdx.x;  // b*32 + g, 256 total
    const float4* p4 = (const float4*)(x + (size_t)grp * (CPG * NHW));
    float s = 0.f, s2 = 0.f;
    for (int i = threadIdx.x; i < CPG * NHW / 4; i += 256) {
        float4 v = p4[i];
        s  += v.x + v.y + v.z + v.w;
        s2 += v.x * v.x + v.y * v.y + v.z * v.z + v.w * v.w;
    }
    for (int off = 32; off > 0; off >>= 1) {
        s  += __shfl_down(s, off);
        s2 += __shfl_down(s2, off);
    }
    __shared__ float ls[4], ls2[4];
    const int wv = threadIdx.x >> 6;
    if ((threadIdx.x & 63) == 0) { ls[wv] = s; ls2[wv] = s2; }
    __syncthreads();
    if (threadIdx.x == 0) {
        float S  = ls[0] + ls[1] + ls[2] + ls[3];
        float S2 = ls2[0] + ls2[1] + ls2[2] + ls2[3];
        const float inv = 1.f / (float)(CPG * NHW);
        float m = S * inv;
        float var = S2 * inv - m * m;
        mu[grp]   = m;
        rinv[grp] = rsqrtf(var + EPS);
    }
}

// ---------------- GN1 apply: hn = (x-mu)*rinv*scale + bias ----------------
__global__ __launch_bounds__(256) void gn_apply_k(const float* __restrict__ x,
                                                  const float* __restrict__ mu,
                                                  const float* __restrict__ rinv,
                                                  const float* __restrict__ sc,
                                                  const float* __restrict__ bi,
                                                  float* __restrict__ hn) {
    const int i4 = blockIdx.x * 256 + threadIdx.x;      // float4 index
    const int c  = (i4 >> 8) & (NC - 1);                // (i4*4/1024)%512
    const int b  = i4 >> 17;
    const int grp = b * NG + (c >> 4);
    const float m = mu[grp], r = rinv[grp];
    const float a = sc[c] * r;
    const float d = bi[c] - m * a;
    float4 v = ((const float4*)x)[i4];
    float4 o = make_float4(v.x * a + d, v.y * a + d, v.z * a + d, v.w * a + d);
    ((float4*)hn)[i4] = o;
}

// ---------------- fp32 tiled GEMM: Y[z][m][n] = sum_k W[m][k]*X[z][k][n] + bias[m] ----------------
// 64x64 tile, BK=16, 256 threads, 4x4 accumulators/thread. n-dim fixed at NHW=1024.
__global__ __launch_bounds__(256) void gemm_k(const float* __restrict__ W,
                                              const float* __restrict__ X,
                                              const float* __restrict__ bias,
                                              float* __restrict__ Y,
                                              int M, int K) {
    __shared__ float As[16][65];  // As[k][m] (W tile transposed)
    __shared__ float Bs[16][65];  // Bs[k][n]
    const int tx = threadIdx.x & 15, ty = threadIdx.x >> 4;
    const int m0 = blockIdx.x * 64;
    const int n0 = blockIdx.y * 64;
    const float* Xb = X + (size_t)blockIdx.z * K * NHW;
    float* Yb = Y + (size_t)blockIdx.z * (size_t)M * NHW;
    const int lm = threadIdx.x >> 2;          // 0..63
    const int lk = (threadIdx.x & 3) << 2;    // 0,4,8,12
    const int lr = threadIdx.x >> 4;          // 0..15
    const int lc = (threadIdx.x & 15) << 2;   // 0..60
    float acc[4][4] = {};
    for (int k0 = 0; k0 < K; k0 += 16) {
        float4 w4 = *(const float4*)&W[(size_t)(m0 + lm) * K + k0 + lk];
        float4 x4 = *(const float4*)&Xb[(size_t)(k0 + lr) * NHW + n0 + lc];
        As[lk + 0][lm] = w4.x; As[lk + 1][lm] = w4.y;
        As[lk + 2][lm] = w4.z; As[lk + 3][lm] = w4.w;
        Bs[lr][lc + 0] = x4.x; Bs[lr][lc + 1] = x4.y;
        Bs[lr][lc + 2] = x4.z; Bs[lr][lc + 3] = x4.w;
        __syncthreads();
        #pragma unroll
        for (int kk = 0; kk < 16; kk++) {
            float av[4], bv[4];
            #pragma unroll
            for (int i = 0; i < 4; i++) av[i] = As[kk][ty * 4 + i];
            #pragma unroll
            for (int j = 0; j < 4; j++) bv[j] = Bs[kk][tx * 4 + j];
            #pragma unroll
            for (int i = 0; i < 4; i++)
                #pragma unroll
                for (int j = 0; j < 4; j++)
                    acc[i][j] += av[i] * bv[j];
        }
        __syncthreads();
    }
    #pragma unroll
    for (int i = 0; i < 4; i++) {
        float bb = bias[m0 + ty * 4 + i];
        float4 o = make_float4(acc[i][0] + bb, acc[i][1] + bb,
                               acc[i][2] + bb, acc[i][3] + bb);
        *(float4*)&Yb[(size_t)(m0 + ty * 4 + i) * NHW + n0 + tx * 4] = o;
    }
}

// ---------------- Flash-style attention ----------------
// grid: (64 bh, 16 query-tiles), block 256. qkv layout: [bh][192][1024]
// (q = rows 0..63, k = 64..127, v = 128..191). S=q^T k * 0.125, online softmax, O = V P^T.
__global__ __launch_bounds__(256) void attn_k(const float* __restrict__ qkv,
                                              float* __restrict__ aout) {
    __shared__ float Qs[64][65];   // [c][t], pre-scaled
    __shared__ float KVs[64][65];  // [c][s], holds K then V
    __shared__ float Ss[64][65];   // [t][s], scores then probabilities
    __shared__ float mrow[64], lrow[64], arow[64];
    const int bh  = blockIdx.x;
    const int t0g = blockIdx.y * 64;
    const float* qb = qkv + (size_t)bh * 192 * NHW;
    const float* kb = qb + 64 * NHW;
    const float* vb = qb + 128 * NHW;
    const int tx = threadIdx.x & 15, ty = threadIdx.x >> 4;
    const int lc = threadIdx.x >> 2;         // 0..63 (channel row)
    const int l4 = (threadIdx.x & 3) << 4;   // 0,16,32,48 (col start)
    const float scale2 = 0.125f;             // ch^-0.5 = 1/sqrt(64)

    #pragma unroll
    for (int j = 0; j < 16; j += 4) {
        float4 q4 = *(const float4*)&qb[(size_t)lc * NHW + t0g + l4 + j];
        Qs[lc][l4 + j + 0] = q4.x * scale2;
        Qs[lc][l4 + j + 1] = q4.y * scale2;
        Qs[lc][l4 + j + 2] = q4.z * scale2;
        Qs[lc][l4 + j + 3] = q4.w * scale2;
    }
    if (threadIdx.x < 64) { mrow[threadIdx.x] = -1e30f; lrow[threadIdx.x] = 0.f; }
    float Oc[4][4] = {};  // [c_i][t_j]: c = tx*4+i, t = ty*4+j
    __syncthreads();

    for (int s0 = 0; s0 < NHW; s0 += 64) {
        // load K tile
        #pragma unroll
        for (int j = 0; j < 16; j += 4) {
            float4 k4 = *(const float4*)&kb[(size_t)lc * NHW + s0 + l4 + j];
            KVs[lc][l4 + j + 0] = k4.x; KVs[lc][l4 + j + 1] = k4.y;
            KVs[lc][l4 + j + 2] = k4.z; KVs[lc][l4 + j + 3] = k4.w;
        }
        __syncthreads();
        // S[t][s] = sum_c Qs[c][t]*KVs[c][s]
        float sacc[4][4] = {};
        #pragma unroll 8
        for (int cc = 0; cc < 64; cc++) {
            float qv[4], kv2[4];
            #pragma unroll
            for (int i = 0; i < 4; i++) qv[i] = Qs[cc][ty * 4 + i];
            #pragma unroll
            for (int j = 0; j < 4; j++) kv2[j] = KVs[cc][tx * 4 + j];
            #pragma unroll
            for (int i = 0; i < 4; i++)
                #pragma unroll
                for (int j = 0; j < 4; j++)
                    sacc[i][j] += qv[i] * kv2[j];
        }
        #pragma unroll
        for (int i = 0; i < 4; i++)
            #pragma unroll
            for (int j = 0; j < 4; j++)
                Ss[ty * 4 + i][tx * 4 + j] = sacc[i][j];
        __syncthreads();
        // load V tile into KVs (all threads) + online softmax on Ss (first 64)
        #pragma unroll
        for (int j = 0; j < 16; j += 4) {
            float4 v4 = *(const float4*)&vb[(size_t)lc * NHW + s0 + l4 + j];
            KVs[lc][l4 + j + 0] = v4.x; KVs[lc][l4 + j + 1] = v4.y;
            KVs[lc][l4 + j + 2] = v4.z; KVs[lc][l4 + j + 3] = v4.w;
        }
        if (threadIdx.x < 64) {
            const int t = threadIdx.x;
            float mold = mrow[t];
            float mx = mold;
            for (int s = 0; s < 64; s++) mx = fmaxf(mx, Ss[t][s]);
            float al = __expf(mold - mx);
            float sum = 0.f;
            for (int s = 0; s < 64; s++) {
                float pp = __expf(Ss[t][s] - mx);
                Ss[t][s] = pp;
                sum += pp;
            }
            mrow[t] = mx;
            lrow[t] = lrow[t] * al + sum;
            arow[t] = al;
        }
        __syncthreads();
        // rescale O, accumulate O[c][t] += sum_s V[c][s] * P[t][s]
        float alj[4];
        #pragma unroll
        for (int j = 0; j < 4; j++) alj[j] = arow[ty * 4 + j];
        #pragma unroll
        for (int i = 0; i < 4; i++)
            #pragma unroll
            for (int j = 0; j < 4; j++)
                Oc[i][j] *= alj[j];
        #pragma unroll 8
        for (int s = 0; s < 64; s++) {
            float vv[4], pp[4];
            #pragma unroll
            for (int i = 0; i < 4; i++) vv[i] = KVs[tx * 4 + i][s];
            #pragma unroll
            for (int j = 0; j < 4; j++) pp[j] = Ss[ty * 4 + j][s];
            #pragma unroll
            for (int i = 0; i < 4; i++)
                #pragma unroll
                for (int j = 0; j < 4; j++)
                    Oc[i][j] += vv[i] * pp[j];
        }
        __syncthreads();
    }
    float linv[4];
    #pragma unroll
    for (int j = 0; j < 4; j++) linv[j] = 1.0f / lrow[ty * 4 + j];
    float* ab = aout + (size_t)bh * 64 * NHW + t0g;
    #pragma unroll
    for (int i = 0; i < 4; i++) {
        float4 o = make_float4(Oc[i][0] * linv[0], Oc[i][1] * linv[1],
                               Oc[i][2] * linv[2], Oc[i][3] * linv[3]);
        *(float4*)&ab[(size_t)(tx * 4 + i) * NHW + ty * 4] = o;
    }
}

// ---------------- final: out = x + GN2(proj) ----------------
__global__ __launch_bounds__(256) void final_k(const float* __restrict__ x,
                                               const float* __restrict__ p,
                                               const float* __restrict__ mu,
                                               const float* __restrict__ rinv,
                                               const float* __restrict__ sc,
                                               const float* __restrict__ bi,
                                               float* __restrict__ out) {
    const int i4 = blockIdx.x * 256 + threadIdx.x;
    const int c  = (i4 >> 8) & (NC - 1);
    const int b  = i4 >> 17;
    const int grp = b * NG + (c >> 4);
    const float m = mu[grp], r = rinv[grp];
    const float a = sc[c] * r;
    const float d = bi[c] - m * a;
    float4 xv = ((const float4*)x)[i4];
    float4 pv = ((const float4*)p)[i4];
    float4 o = make_float4(xv.x + pv.x * a + d, xv.y + pv.y * a + d,
                           xv.z + pv.z * a + d, xv.w + pv.w * a + d);
    ((float4*)out)[i4] = o;
}

extern "C" void kernel_launch(void* const* d_in, const int* in_sizes, int n_in,
                              void* d_out, int out_size, void* d_ws, size_t ws_size,
                              hipStream_t stream) {
    const float* x      = (const float*)d_in[0];
    const float* gn1_s  = (const float*)d_in[1];
    const float* gn1_b  = (const float*)d_in[2];
    const float* w_qkv  = (const float*)d_in[3];
    const float* b_qkv  = (const float*)d_in[4];
    const float* w_proj = (const float*)d_in[5];
    const float* b_proj = (const float*)d_in[6];
    const float* gn2_s  = (const float*)d_in[7];
    const float* gn2_b  = (const float*)d_in[8];
    float* out = (float*)d_out;

    // workspace: buf1 = hn, then attention output (4,194,304 floats)
    //            buf2 = qkv, then proj output   (12,582,912 floats)
    float* buf1 = (float*)d_ws;
    float* buf2 = buf1 + 4194304;
    float* mu1  = buf2 + 12582912;
    float* ri1  = mu1 + 256;
    float* mu2  = ri1 + 256;
    float* ri2  = mu2 + 256;

    gn_stats_k<<<256, 256, 0, stream>>>(x, mu1, ri1);
    gn_apply_k<<<4096, 256, 0, stream>>>(x, mu1, ri1, gn1_s, gn1_b, buf1);

    dim3 g1(QKV_C / 64, NHW / 64, NB);
    gemm_k<<<g1, 256, 0, stream>>>(w_qkv, buf1, b_qkv, buf2, QKV_C, NC);

    dim3 g2(64, 16);
    attn_k<<<g2, 256, 0, stream>>>(buf2, buf1);

    dim3 g3(NC / 64, NHW / 64, NB);
    gemm_k<<<g3, 256, 0, stream>>>(w_proj, buf1, b_proj, buf2, NC, NC);

    gn_stats_k<<<256, 256, 0, stream>>>(buf2, mu2, ri2);
    final_k<<<4096, 256, 0, stream>>>(x, buf2, mu2, ri2, gn2_s, gn2_b, out);
}

// Round 2
// 215.992 us; speedup vs baseline: 3.7452x; 3.7452x over previous
//
#include <hip/hip_runtime.h>
#include <math.h>

#define NB 8
#define NC 512
#define NHW 1024
#define NG 32
#define CPG 16
#define QKV_C 1536
#define EPS 1e-5f

typedef float  f32x4  __attribute__((ext_vector_type(4)));
typedef __bf16 bf16x8 __attribute__((ext_vector_type(8)));
typedef __bf16 bf16x4 __attribute__((ext_vector_type(4)));

__device__ __forceinline__ void gload_lds16(const void* g, void* l) {
    __builtin_amdgcn_global_load_lds(
        (const __attribute__((address_space(1))) void*)g,
        (__attribute__((address_space(3))) void*)l, 16, 0, 0);
}

// ---------------- GroupNorm statistics: one block per (b,g) group ----------------
__global__ __launch_bounds__(256) void gn_stats_k(const float* __restrict__ x,
                                                  float* __restrict__ mu,
                                                  float* __restrict__ rinv) {
    const int grp = blockIdx.x;  // b*32 + g
    const float4* p4 = (const float4*)(x + (size_t)grp * (CPG * NHW));
    float s = 0.f, s2 = 0.f;
    for (int i = threadIdx.x; i < CPG * NHW / 4; i += 256) {
        float4 v = p4[i];
        s  += v.x + v.y + v.z + v.w;
        s2 += v.x * v.x + v.y * v.y + v.z * v.z + v.w * v.w;
    }
    for (int off = 32; off > 0; off >>= 1) {
        s  += __shfl_down(s, off);
        s2 += __shfl_down(s2, off);
    }
    __shared__ float ls[4], ls2[4];
    const int wv = threadIdx.x >> 6;
    if ((threadIdx.x & 63) == 0) { ls[wv] = s; ls2[wv] = s2; }
    __syncthreads();
    if (threadIdx.x == 0) {
        float S  = ls[0] + ls[1] + ls[2] + ls[3];
        float S2 = ls2[0] + ls2[1] + ls2[2] + ls2[3];
        const float inv = 1.f / (float)(CPG * NHW);
        float m = S * inv;
        float var = S2 * inv - m * m;
        mu[grp]   = m;
        rinv[grp] = rsqrtf(var + EPS);
    }
}

// ---------------- GN1 apply + transpose: hnT[b][n][c] bf16 ----------------
__global__ __launch_bounds__(256) void gn_apply_t_k(const float* __restrict__ x,
                                                    const float* __restrict__ mu,
                                                    const float* __restrict__ rinv,
                                                    const float* __restrict__ sc,
                                                    const float* __restrict__ bi,
                                                    __bf16* __restrict__ hnT) {
    __shared__ float T[64][65];
    const int tid = threadIdx.x;
    const int nb = blockIdx.x * 64, cb = blockIdx.y * 64, b = blockIdx.z;
    const int col = (tid & 15) * 4;
    const int rb = tid >> 4;
    #pragma unroll
    for (int rr = 0; rr < 4; rr++) {
        int cl = rr * 16 + rb;
        int c = cb + cl;
        int grp = b * NG + (c >> 4);
        float a = sc[c] * rinv[grp];
        float d = bi[c] - mu[grp] * a;
        float4 v4 = *(const float4*)&x[((size_t)(b * NC + c)) * NHW + nb + col];
        T[cl][col + 0] = v4.x * a + d;
        T[cl][col + 1] = v4.y * a + d;
        T[cl][col + 2] = v4.z * a + d;
        T[cl][col + 3] = v4.w * a + d;
    }
    __syncthreads();
    const int nl = tid >> 2;
    const int c0 = (tid & 3) * 16;
    bf16x8 o0, o1;
    #pragma unroll
    for (int i = 0; i < 8; i++) o0[i] = (__bf16)T[c0 + i][nl];
    #pragma unroll
    for (int i = 0; i < 8; i++) o1[i] = (__bf16)T[c0 + 8 + i][nl];
    __bf16* dst = hnT + ((size_t)(b * NHW + nb + nl)) * NC + cb + c0;
    *(bf16x8*)dst = o0;
    *(bf16x8*)(dst + 8) = o1;
}

// ---------------- fp32 -> bf16 convert ----------------
__global__ __launch_bounds__(256) void cvt_k(const float* __restrict__ s,
                                             __bf16* __restrict__ d) {
    const int i = blockIdx.x * 256 + threadIdx.x;
    float4 v = ((const float4*)s)[i];
    bf16x4 o;
    o[0] = (__bf16)v.x; o[1] = (__bf16)v.y; o[2] = (__bf16)v.z; o[3] = (__bf16)v.w;
    ((bf16x4*)d)[i] = o;
}

// ---------------- MFMA GEMM core: 128x128 tile, BK=32, 256 threads ----------------
// W [M][K] bf16 row-major; Bm [N][K] bf16 row-major (i.e. B^T). acc[mi][ni] 16x16 tiles.
__device__ __forceinline__ void mm_core(const __bf16* __restrict__ W,
                                        const __bf16* __restrict__ Bm,
                                        int K, int m0, int n0,
                                        __bf16* As, __bf16* Bs,
                                        f32x4 (&acc)[4][4]) {
    const int tid = threadIdx.x;
    const int w = tid >> 6, lane = tid & 63;
    const int l15 = lane & 15, quad = lane >> 4;
    const int wm = (w & 1) * 64, wn = (w >> 1) * 64;
    const int lr = lane >> 2, lk = (lane & 3) * 8;
    for (int k0 = 0; k0 < K; k0 += 32) {
        #pragma unroll
        for (int i = 0; i < 2; i++) {
            int rb = (w * 2 + i) * 16;
            gload_lds16(W  + (size_t)(m0 + rb + lr) * K + k0 + lk, As + rb * 32);
            gload_lds16(Bm + (size_t)(n0 + rb + lr) * K + k0 + lk, Bs + rb * 32);
        }
        __syncthreads();
        bf16x8 af[4], bfv[4];
        #pragma unroll
        for (int mi = 0; mi < 4; mi++)
            af[mi] = *(const bf16x8*)(As + (wm + mi * 16 + l15) * 32 + quad * 8);
        #pragma unroll
        for (int ni = 0; ni < 4; ni++)
            bfv[ni] = *(const bf16x8*)(Bs + (wn + ni * 16 + l15) * 32 + quad * 8);
        #pragma unroll
        for (int mi = 0; mi < 4; mi++)
            #pragma unroll
            for (int ni = 0; ni < 4; ni++)
                acc[mi][ni] = __builtin_amdgcn_mfma_f32_16x16x32_bf16(
                    af[mi], bfv[ni], acc[mi][ni], 0, 0, 0);
        __syncthreads();
    }
}

// ---------------- QKV GEMM: out -> qT[bh][n][64], kT[bh][n][64], v[bh][c][n] (bf16) ----------------
__global__ __launch_bounds__(256) void qkv_gemm_k(const __bf16* __restrict__ W,
                                                  const __bf16* __restrict__ hnT,
                                                  const float* __restrict__ bias,
                                                  __bf16* __restrict__ qT,
                                                  __bf16* __restrict__ kT,
                                                  __bf16* __restrict__ v) {
    __shared__ __bf16 As[128 * 32];
    __shared__ __bf16 Bs[128 * 32];
    const int m0 = blockIdx.x * 128, n0 = blockIdx.y * 128, b = blockIdx.z;
    f32x4 acc[4][4] = {};
    mm_core(W, hnT + (size_t)b * NHW * NC, NC, m0, n0, As, Bs, acc);
    const int tid = threadIdx.x;
    const int w = tid >> 6, lane = tid & 63;
    const int l15 = lane & 15, quad = lane >> 4;
    const int wm = (w & 1) * 64, wn = (w >> 1) * 64;
    #pragma unroll
    for (int mi = 0; mi < 4; mi++) {
        #pragma unroll
        for (int r = 0; r < 4; r++) {
            int m = m0 + wm + mi * 16 + quad * 4 + r;
            float bb = bias[m];
            int h = m / 192;
            int rr = m - h * 192;
            int bh = b * 8 + h;
            #pragma unroll
            for (int ni = 0; ni < 4; ni++) {
                int n = n0 + wn + ni * 16 + l15;
                float val = acc[mi][ni][r] + bb;
                if (rr < 64) {
                    qT[((size_t)bh << 16) + n * 64 + rr] = (__bf16)val;
                } else if (rr < 128) {
                    kT[((size_t)bh << 16) + n * 64 + (rr - 64)] = (__bf16)val;
                } else {
                    v[((size_t)(bh * 64 + rr - 128)) * NHW + n] = (__bf16)val;
                }
            }
        }
    }
}

// ---------------- proj GEMM: proj[b][m][n] fp32 ----------------
__global__ __launch_bounds__(256) void proj_gemm_k(const __bf16* __restrict__ W,
                                                   const __bf16* __restrict__ aT,
                                                   const float* __restrict__ bias,
                                                   float* __restrict__ proj) {
    __shared__ __bf16 As[128 * 32];
    __shared__ __bf16 Bs[128 * 32];
    const int m0 = blockIdx.x * 128, n0 = blockIdx.y * 128, b = blockIdx.z;
    f32x4 acc[4][4] = {};
    mm_core(W, aT + (size_t)b * NHW * NC, NC, m0, n0, As, Bs, acc);
    const int tid = threadIdx.x;
    const int w = tid >> 6, lane = tid & 63;
    const int l15 = lane & 15, quad = lane >> 4;
    const int wm = (w & 1) * 64, wn = (w >> 1) * 64;
    #pragma unroll
    for (int mi = 0; mi < 4; mi++) {
        #pragma unroll
        for (int r = 0; r < 4; r++) {
            int m = m0 + wm + mi * 16 + quad * 4 + r;
            float bb = bias[m];
            #pragma unroll
            for (int ni = 0; ni < 4; ni++) {
                int n = n0 + wn + ni * 16 + l15;
                proj[((size_t)(b * NC + m)) * NHW + n] = acc[mi][ni][r] + bb;
            }
        }
    }
}

// ---------------- MFMA flash attention ----------------
// grid (64 bh, 16 q-tiles), 256 threads. qT/kT: [bh][n][64]; v: [bh][c][n]; out aT: [b][n][512]
__global__ __launch_bounds__(256) void attn_k(const __bf16* __restrict__ qT,
                                              const __bf16* __restrict__ kT,
                                              const __bf16* __restrict__ vv,
                                              __bf16* __restrict__ aT) {
    __shared__ __bf16 Qt[2 * 64 * 32];   // [c-chunk][t][32]
    __shared__ __bf16 Kt[2 * 64 * 32];   // [c-chunk][s][32]
    __shared__ __bf16 Vt[2 * 64 * 32];   // [s-chunk][c][32]
    __shared__ __bf16 Ps[64 * 72];       // [t][s], pitch 72
    const int tid = threadIdx.x;
    const int w = tid >> 6, lane = tid & 63;
    const int l15 = lane & 15, quad = lane >> 4;
    const int lr = lane >> 2, lk = (lane & 3) * 8;
    const int bh = blockIdx.x, t0 = blockIdx.y * 64;
    const __bf16* qb = qT + ((size_t)bh << 16);
    const __bf16* kb = kT + ((size_t)bh << 16);
    const __bf16* vb = vv + ((size_t)bh << 6) * NHW;

    // stage Q tile: layout [ch][t][32], 8 instrs total
    #pragma unroll
    for (int i = 0; i < 2; i++) {
        int inst = w * 2 + i;
        int ch = inst >> 2, tb = (inst & 3) * 16;
        gload_lds16(qb + (size_t)(t0 + tb + lr) * 64 + ch * 32 + lk,
                    Qt + ch * 2048 + tb * 32);
    }
    float mrun[4], lrun[4];
    #pragma unroll
    for (int r = 0; r < 4; r++) { mrun[r] = -1e30f; lrun[r] = 0.f; }
    f32x4 Oacc[4] = {};

    for (int s0 = 0; s0 < NHW; s0 += 64) {
        #pragma unroll
        for (int i = 0; i < 4; i++) {
            int inst = w * 4 + i;
            if (inst < 8) {
                int ch = inst >> 2, sb = (inst & 3) * 16;
                gload_lds16(kb + (size_t)(s0 + sb + lr) * 64 + ch * 32 + lk,
                            Kt + ch * 2048 + sb * 32);
            } else {
                int i2 = inst - 8;
                int ch = i2 >> 2, cb = (i2 & 3) * 16;
                gload_lds16(vb + (size_t)(cb + lr) * NHW + s0 + ch * 32 + lk,
                            Vt + ch * 2048 + cb * 32);
            }
        }
        __syncthreads();
        // S = Q^T K (wave w owns t-rows [16w,16w+16))
        f32x4 sacc[4] = {};
        #pragma unroll
        for (int ch = 0; ch < 2; ch++) {
            bf16x8 a = *(const bf16x8*)(Qt + ch * 2048 + (w * 16 + l15) * 32 + quad * 8);
            #pragma unroll
            for (int j = 0; j < 4; j++) {
                bf16x8 bfr = *(const bf16x8*)(Kt + ch * 2048 + (j * 16 + l15) * 32 + quad * 8);
                sacc[j] = __builtin_amdgcn_mfma_f32_16x16x32_bf16(a, bfr, sacc[j], 0, 0, 0);
            }
        }
        #pragma unroll
        for (int j = 0; j < 4; j++)
            #pragma unroll
            for (int r = 0; r < 4; r++)
                sacc[j][r] *= 0.125f;
        // online softmax (rows t = w*16 + quad*4 + r live across the quad's 16 lanes)
        float alpha[4];
        #pragma unroll
        for (int r = 0; r < 4; r++) {
            float mx = fmaxf(fmaxf(sacc[0][r], sacc[1][r]), fmaxf(sacc[2][r], sacc[3][r]));
            mx = fmaxf(mx, __shfl_xor(mx, 1));
            mx = fmaxf(mx, __shfl_xor(mx, 2));
            mx = fmaxf(mx, __shfl_xor(mx, 4));
            mx = fmaxf(mx, __shfl_xor(mx, 8));
            float mn = fmaxf(mrun[r], mx);
            float al = __expf(mrun[r] - mn);
            float sum = 0.f;
            int t = w * 16 + quad * 4 + r;
            #pragma unroll
            for (int j = 0; j < 4; j++) {
                float p = __expf(sacc[j][r] - mn);
                Ps[t * 72 + j * 16 + l15] = (__bf16)p;
                sum += p;
            }
            sum += __shfl_xor(sum, 1);
            sum += __shfl_xor(sum, 2);
            sum += __shfl_xor(sum, 4);
            sum += __shfl_xor(sum, 8);
            lrun[r] = lrun[r] * al + sum;
            mrun[r] = mn;
            alpha[r] = al;
        }
        #pragma unroll
        for (int ci = 0; ci < 4; ci++)
            #pragma unroll
            for (int r = 0; r < 4; r++)
                Oacc[ci][r] *= alpha[r];
        // O^T[t][c] += P V^T  (Ps written/read by same wave)
        #pragma unroll
        for (int ch = 0; ch < 2; ch++) {
            bf16x8 a = *(const bf16x8*)(Ps + (w * 16 + l15) * 72 + ch * 32 + quad * 8);
            #pragma unroll
            for (int ci = 0; ci < 4; ci++) {
                bf16x8 bfr = *(const bf16x8*)(Vt + ch * 2048 + (ci * 16 + l15) * 32 + quad * 8);
                Oacc[ci] = __builtin_amdgcn_mfma_f32_16x16x32_bf16(a, bfr, Oacc[ci], 0, 0, 0);
            }
        }
        __syncthreads();
    }
    const int b = bh >> 3, hh = bh & 7;
    #pragma unroll
    for (int r = 0; r < 4; r++) {
        float inv = 1.f / lrun[r];
        int t = w * 16 + quad * 4 + r;
        size_t base = ((size_t)(b * NHW + t0 + t)) * NC + hh * 64;
        #pragma unroll
        for (int ci = 0; ci < 4; ci++)
            aT[base + ci * 16 + l15] = (__bf16)(Oacc[ci][r] * inv);
    }
}

// ---------------- final: out = x + GN2(proj) ----------------
__global__ __launch_bounds__(256) void final_k(const float* __restrict__ x,
                                               const float* __restrict__ p,
                                               const float* __restrict__ mu,
                                               const float* __restrict__ rinv,
                                               const float* __restrict__ sc,
                                               const float* __restrict__ bi,
                                               float* __restrict__ out) {
    const int i4 = blockIdx.x * 256 + threadIdx.x;
    const int c  = (i4 >> 8) & (NC - 1);
    const int b  = i4 >> 17;
    const int grp = b * NG + (c >> 4);
    const float m = mu[grp], r = rinv[grp];
    const float a = sc[c] * r;
    const float d = bi[c] - m * a;
    float4 xv = ((const float4*)x)[i4];
    float4 pv = ((const float4*)p)[i4];
    float4 o = make_float4(xv.x + pv.x * a + d, xv.y + pv.y * a + d,
                           xv.z + pv.z * a + d, xv.w + pv.w * a + d);
    ((float4*)out)[i4] = o;
}

extern "C" void kernel_launch(void* const* d_in, const int* in_sizes, int n_in,
                              void* d_out, int out_size, void* d_ws, size_t ws_size,
                              hipStream_t stream) {
    const float* x      = (const float*)d_in[0];
    const float* gn1_s  = (const float*)d_in[1];
    const float* gn1_b  = (const float*)d_in[2];
    const float* w_qkv  = (const float*)d_in[3];
    const float* b_qkv  = (const float*)d_in[4];
    const float* w_proj = (const float*)d_in[5];
    const float* b_proj = (const float*)d_in[6];
    const float* gn2_s  = (const float*)d_in[7];
    const float* gn2_b  = (const float*)d_in[8];
    float* out = (float*)d_out;

    // workspace carve-up (bytes, all 16B-aligned)
    char* p = (char*)d_ws;
    __bf16* hnT  = (__bf16*)p;            p += (size_t)8 * 1024 * 512 * 2;   // 8 MB
    __bf16* qT   = (__bf16*)p;            p += (size_t)64 * 1024 * 64 * 2;   // 8 MB
    __bf16* kT   = (__bf16*)p;            p += (size_t)64 * 1024 * 64 * 2;   // 8 MB
    __bf16* vB   = (__bf16*)p;            p += (size_t)64 * 64 * 1024 * 2;   // 8 MB
    __bf16* aT   = (__bf16*)p;            p += (size_t)8 * 1024 * 512 * 2;   // 8 MB
    float*  proj = (float*)p;             p += (size_t)8 * 512 * 1024 * 4;   // 16 MB
    __bf16* wq   = (__bf16*)p;            p += (size_t)QKV_C * NC * 2;       // 1.5 MB
    __bf16* wp   = (__bf16*)p;            p += (size_t)NC * NC * 2;          // 0.5 MB
    float*  mu1  = (float*)p;             p += 256 * 4;
    float*  ri1  = (float*)p;             p += 256 * 4;
    float*  mu2  = (float*)p;             p += 256 * 4;
    float*  ri2  = (float*)p;             p += 256 * 4;

    gn_stats_k<<<256, 256, 0, stream>>>(x, mu1, ri1);
    cvt_k<<<QKV_C * NC / 1024, 256, 0, stream>>>(w_qkv, wq);
    cvt_k<<<NC * NC / 1024, 256, 0, stream>>>(w_proj, wp);
    gn_apply_t_k<<<dim3(16, 8, 8), 256, 0, stream>>>(x, mu1, ri1, gn1_s, gn1_b, hnT);

    qkv_gemm_k<<<dim3(12, 8, 8), 256, 0, stream>>>(wq, hnT, b_qkv, qT, kT, vB);

    attn_k<<<dim3(64, 16), 256, 0, stream>>>(qT, kT, vB, aT);

    proj_gemm_k<<<dim3(4, 8, 8), 256, 0, stream>>>(wp, aT, b_proj, proj);

    gn_stats_k<<<256, 256, 0, stream>>>(proj, mu2, ri2);
    final_k<<<4096, 256, 0, stream>>>(x, proj, mu2, ri2, gn2_s, gn2_b, out);
}

// Round 4
// 195.685 us; speedup vs baseline: 4.1339x; 1.1038x over previous
//
#include <hip/hip_runtime.h>
#include <math.h>

#define NB 8
#define NC 512
#define NHW 1024
#define NG 32
#define CPG 16
#define QKV_C 1536
#define EPS 1e-5f
#define QSCALE 0.18033688011112042f   // 0.125 * log2(e)

typedef float  f32x4  __attribute__((ext_vector_type(4)));
typedef __bf16 bf16x8 __attribute__((ext_vector_type(8)));
typedef __bf16 bf16x4 __attribute__((ext_vector_type(4)));

__device__ __forceinline__ void gload_lds16(const void* g, void* l) {
    __builtin_amdgcn_global_load_lds(
        (const __attribute__((address_space(1))) void*)g,
        (__attribute__((address_space(3))) void*)l, 16, 0, 0);
}

// Drain this wave's outstanding global_load_lds DMA. MUST precede any
// __syncthreads() that publishes DMA-written LDS to other waves: the DMA is
// counted by vmcnt and the compiler cannot see the LDS dependency, so it may
// omit the vmcnt(0) drain before s_barrier (R3 post-timing divergence).
__device__ __forceinline__ void dma_drain() {
    asm volatile("s_waitcnt vmcnt(0)" ::: "memory");
}

// ---------------- GroupNorm statistics: one block per (b,g) group ----------------
__global__ __launch_bounds__(256) void gn_stats_k(const float* __restrict__ x,
                                                  float* __restrict__ mu,
                                                  float* __restrict__ rinv) {
    const int grp = blockIdx.x;  // b*32 + g
    const float4* p4 = (const float4*)(x + (size_t)grp * (CPG * NHW));
    float s = 0.f, s2 = 0.f;
    for (int i = threadIdx.x; i < CPG * NHW / 4; i += 256) {
        float4 v = p4[i];
        s  += v.x + v.y + v.z + v.w;
        s2 += v.x * v.x + v.y * v.y + v.z * v.z + v.w * v.w;
    }
    for (int off = 32; off > 0; off >>= 1) {
        s  += __shfl_down(s, off);
        s2 += __shfl_down(s2, off);
    }
    __shared__ float ls[4], ls2[4];
    const int wv = threadIdx.x >> 6;
    if ((threadIdx.x & 63) == 0) { ls[wv] = s; ls2[wv] = s2; }
    __syncthreads();
    if (threadIdx.x == 0) {
        float S  = ls[0] + ls[1] + ls[2] + ls[3];
        float S2 = ls2[0] + ls2[1] + ls2[2] + ls2[3];
        const float inv = 1.f / (float)(CPG * NHW);
        float m = S * inv;
        float var = S2 * inv - m * m;
        mu[grp]   = m;
        rinv[grp] = rsqrtf(var + EPS);
    }
}

// ---------------- GN1 apply + transpose: hnT[b][n][c] bf16 ----------------
__global__ __launch_bounds__(256) void gn_apply_t_k(const float* __restrict__ x,
                                                    const float* __restrict__ mu,
                                                    const float* __restrict__ rinv,
                                                    const float* __restrict__ sc,
                                                    const float* __restrict__ bi,
                                                    __bf16* __restrict__ hnT) {
    __shared__ float T[64][65];
    const int tid = threadIdx.x;
    const int nb = blockIdx.x * 64, cb = blockIdx.y * 64, b = blockIdx.z;
    const int col = (tid & 15) * 4;
    const int rb = tid >> 4;
    #pragma unroll
    for (int rr = 0; rr < 4; rr++) {
        int cl = rr * 16 + rb;
        int c = cb + cl;
        int grp = b * NG + (c >> 4);
        float a = sc[c] * rinv[grp];
        float d = bi[c] - mu[grp] * a;
        float4 v4 = *(const float4*)&x[((size_t)(b * NC + c)) * NHW + nb + col];
        T[cl][col + 0] = v4.x * a + d;
        T[cl][col + 1] = v4.y * a + d;
        T[cl][col + 2] = v4.z * a + d;
        T[cl][col + 3] = v4.w * a + d;
    }
    __syncthreads();
    const int nl = tid >> 2;
    const int c0 = (tid & 3) * 16;
    bf16x8 o0, o1;
    #pragma unroll
    for (int i = 0; i < 8; i++) o0[i] = (__bf16)T[c0 + i][nl];
    #pragma unroll
    for (int i = 0; i < 8; i++) o1[i] = (__bf16)T[c0 + 8 + i][nl];
    __bf16* dst = hnT + ((size_t)(b * NHW + nb + nl)) * NC + cb + c0;
    *(bf16x8*)dst = o0;
    *(bf16x8*)(dst + 8) = o1;
}

// ---------------- fp32 -> bf16 convert (both weight matrices, one launch) --------
__global__ __launch_bounds__(256) void cvt2_k(const float* __restrict__ s1,
                                              __bf16* __restrict__ d1,
                                              const float* __restrict__ s2,
                                              __bf16* __restrict__ d2,
                                              int n1_4) {
    const int i = blockIdx.x * 256 + threadIdx.x;
    const float4* s = (i < n1_4) ? (const float4*)s1 + i : (const float4*)s2 + (i - n1_4);
    bf16x4* d = (i < n1_4) ? (bf16x4*)d1 + i : (bf16x4*)d2 + (i - n1_4);
    float4 v = *s;
    bf16x4 o;
    o[0] = (__bf16)v.x; o[1] = (__bf16)v.y; o[2] = (__bf16)v.z; o[3] = (__bf16)v.w;
    *d = o;
}

// ---------------- MFMA GEMM core: 128x128 tile, BK=32, ping-pong LDS ----------------
// W [M][K] bf16 row-major; Bm [N][K] bf16 row-major (i.e. B^T). acc[mi][ni] 16x16 tiles.
__device__ __forceinline__ void mm_stage(const __bf16* __restrict__ W,
                                         const __bf16* __restrict__ Bm,
                                         int K, int m0, int n0, int k0,
                                         __bf16* As, __bf16* Bs) {
    const int tid = threadIdx.x;
    const int w = tid >> 6, lane = tid & 63;
    const int lr = lane >> 2, lk = (lane & 3) * 8;
    #pragma unroll
    for (int i = 0; i < 2; i++) {
        int rb = (w * 2 + i) * 16;
        gload_lds16(W  + (size_t)(m0 + rb + lr) * K + k0 + lk, As + rb * 32);
        gload_lds16(Bm + (size_t)(n0 + rb + lr) * K + k0 + lk, Bs + rb * 32);
    }
}

__device__ __forceinline__ void mm_core(const __bf16* __restrict__ W,
                                        const __bf16* __restrict__ Bm,
                                        int K, int m0, int n0,
                                        __bf16* As, __bf16* Bs,
                                        f32x4 (&acc)[4][4]) {
    const int tid = threadIdx.x;
    const int w = tid >> 6, lane = tid & 63;
    const int l15 = lane & 15, quad = lane >> 4;
    const int wm = (w & 1) * 64, wn = (w >> 1) * 64;
    const int nk = K >> 5;
    mm_stage(W, Bm, K, m0, n0, 0, As, Bs);
    for (int it = 0; it < nk; it++) {
        const int cur = (it & 1) * 4096;
        dma_drain();           // own DMA (prologue or previous prefetch) has landed
        __syncthreads();
        if (it + 1 < nk)
            mm_stage(W, Bm, K, m0, n0, (it + 1) * 32, As + (4096 - cur), Bs + (4096 - cur));
        bf16x8 af[4], bfv[4];
        #pragma unroll
        for (int mi = 0; mi < 4; mi++)
            af[mi] = *(const bf16x8*)(As + cur + (wm + mi * 16 + l15) * 32 + quad * 8);
        #pragma unroll
        for (int ni = 0; ni < 4; ni++)
            bfv[ni] = *(const bf16x8*)(Bs + cur + (wn + ni * 16 + l15) * 32 + quad * 8);
        #pragma unroll
        for (int mi = 0; mi < 4; mi++)
            #pragma unroll
            for (int ni = 0; ni < 4; ni++)
                acc[mi][ni] = __builtin_amdgcn_mfma_f32_16x16x32_bf16(
                    af[mi], bfv[ni], acc[mi][ni], 0, 0, 0);
    }
}

// ---------------- QKV GEMM: out -> qT[bh][n][64] (pre-scaled), kT[bh][n][64], v[bh][c][n] ----
__global__ __launch_bounds__(256) void qkv_gemm_k(const __bf16* __restrict__ W,
                                                  const __bf16* __restrict__ hnT,
                                                  const float* __restrict__ bias,
                                                  __bf16* __restrict__ qT,
                                                  __bf16* __restrict__ kT,
                                                  __bf16* __restrict__ v) {
    __shared__ __bf16 As[2 * 128 * 32];
    __shared__ __bf16 Bs[2 * 128 * 32];
    const int m0 = blockIdx.x * 128, n0 = blockIdx.y * 128, b = blockIdx.z;
    f32x4 acc[4][4] = {};
    mm_core(W, hnT + (size_t)b * NHW * NC, NC, m0, n0, As, Bs, acc);
    const int tid = threadIdx.x;
    const int w = tid >> 6, lane = tid & 63;
    const int l15 = lane & 15, quad = lane >> 4;
    const int wm = (w & 1) * 64, wn = (w >> 1) * 64;
    #pragma unroll
    for (int mi = 0; mi < 4; mi++) {
        #pragma unroll
        for (int r = 0; r < 4; r++) {
            int m = m0 + wm + mi * 16 + quad * 4 + r;
            float bb = bias[m];
            int h = m / 192;
            int rr = m - h * 192;
            int bh = b * 8 + h;
            #pragma unroll
            for (int ni = 0; ni < 4; ni++) {
                int n = n0 + wn + ni * 16 + l15;
                float val = acc[mi][ni][r] + bb;
                if (rr < 64) {
                    qT[((size_t)bh << 16) + n * 64 + rr] = (__bf16)(val * QSCALE);
                } else if (rr < 128) {
                    kT[((size_t)bh << 16) + n * 64 + (rr - 64)] = (__bf16)val;
                } else {
                    v[((size_t)(bh * 64 + rr - 128)) * NHW + n] = (__bf16)val;
                }
            }
        }
    }
}

// ---------------- proj GEMM: proj[b][m][n] fp32 ----------------
__global__ __launch_bounds__(256) void proj_gemm_k(const __bf16* __restrict__ W,
                                                   const __bf16* __restrict__ aT,
                                                   const float* __restrict__ bias,
                                                   float* __restrict__ proj) {
    __shared__ __bf16 As[2 * 128 * 32];
    __shared__ __bf16 Bs[2 * 128 * 32];
    const int m0 = blockIdx.x * 128, n0 = blockIdx.y * 128, b = blockIdx.z;
    f32x4 acc[4][4] = {};
    mm_core(W, aT + (size_t)b * NHW * NC, NC, m0, n0, As, Bs, acc);
    const int tid = threadIdx.x;
    const int w = tid >> 6, lane = tid & 63;
    const int l15 = lane & 15, quad = lane >> 4;
    const int wm = (w & 1) * 64, wn = (w >> 1) * 64;
    #pragma unroll
    for (int mi = 0; mi < 4; mi++) {
        #pragma unroll
        for (int r = 0; r < 4; r++) {
            int m = m0 + wm + mi * 16 + quad * 4 + r;
            float bb = bias[m];
            #pragma unroll
            for (int ni = 0; ni < 4; ni++) {
                int n = n0 + wn + ni * 16 + l15;
                proj[((size_t)(b * NC + m)) * NHW + n] = acc[mi][ni][r] + bb;
            }
        }
    }
}

// ---------------- MFMA flash attention, no-max softmax, ping-pong K/V ----------------
// grid (64 bh, 16 q-tiles), 256 threads. qT (pre-scaled by 0.125*log2e), kT: [bh][n][64];
// v: [bh][c][n]; out aT: [b][n][512]. p = exp2(S), row-sums accumulated per-lane.
__global__ __launch_bounds__(256) void attn_k(const __bf16* __restrict__ qT,
                                              const __bf16* __restrict__ kT,
                                              const __bf16* __restrict__ vv,
                                              __bf16* __restrict__ aT) {
    __shared__ __bf16 Qt[2 * 64 * 32];       // [ch][t][32]
    __shared__ __bf16 Kt[2 * 2 * 64 * 32];   // 2 buffers
    __shared__ __bf16 Vt[2 * 2 * 64 * 32];   // 2 buffers
    __shared__ __bf16 Ps[64 * 72];           // [t][s], pitch 72
    const int tid = threadIdx.x;
    const int w = tid >> 6, lane = tid & 63;
    const int l15 = lane & 15, quad = lane >> 4;
    const int lr = lane >> 2, lk = (lane & 3) * 8;
    const int bh = blockIdx.x, t0 = blockIdx.y * 64;
    const __bf16* qb = qT + ((size_t)bh << 16);
    const __bf16* kb = kT + ((size_t)bh << 16);
    const __bf16* vb = vv + ((size_t)bh << 6) * NHW;

    // stage Q tile: [ch][t][32]
    #pragma unroll
    for (int i = 0; i < 2; i++) {
        int inst = w * 2 + i;
        int ch = inst >> 2, tb = (inst & 3) * 16;
        gload_lds16(qb + (size_t)(t0 + tb + lr) * 64 + ch * 32 + lk,
                    Qt + ch * 2048 + tb * 32);
    }
    // stage K/V tile 0 into buffer 0
    {
        const int s0 = 0;
        #pragma unroll
        for (int i = 0; i < 4; i++) {
            int inst = w * 4 + i;
            if (inst < 8) {
                int ch = inst >> 2, sb = (inst & 3) * 16;
                gload_lds16(kb + (size_t)(s0 + sb + lr) * 64 + ch * 32 + lk,
                            Kt + ch * 2048 + sb * 32);
            } else {
                int i2 = inst - 8;
                int ch = i2 >> 2, cb = (i2 & 3) * 16;
                gload_lds16(vb + (size_t)(cb + lr) * NHW + s0 + ch * 32 + lk,
                            Vt + ch * 2048 + cb * 32);
            }
        }
    }
    float lpart[4] = {};
    f32x4 Oacc[4] = {};

    for (int it = 0; it < 16; it++) {
        const int cur = (it & 1) * 4096;
        const int nxt = 4096 - cur;
        dma_drain();           // own DMA (tile-0 staging or previous prefetch) landed
        __syncthreads();
        // prefetch next tile
        if (it + 1 < 16) {
            const int s0 = (it + 1) * 64;
            #pragma unroll
            for (int i = 0; i < 4; i++) {
                int inst = w * 4 + i;
                if (inst < 8) {
                    int ch = inst >> 2, sb = (inst & 3) * 16;
                    gload_lds16(kb + (size_t)(s0 + sb + lr) * 64 + ch * 32 + lk,
                                Kt + nxt + ch * 2048 + sb * 32);
                } else {
                    int i2 = inst - 8;
                    int ch = i2 >> 2, cb = (i2 & 3) * 16;
                    gload_lds16(vb + (size_t)(cb + lr) * NHW + s0 + ch * 32 + lk,
                                Vt + nxt + ch * 2048 + cb * 32);
                }
            }
        }
        // S = Q^T K (wave w owns t-rows [16w,16w+16)); Q pre-scaled so P = exp2(S)
        f32x4 sacc[4] = {};
        #pragma unroll
        for (int ch = 0; ch < 2; ch++) {
            bf16x8 a = *(const bf16x8*)(Qt + ch * 2048 + (w * 16 + l15) * 32 + quad * 8);
            #pragma unroll
            for (int j = 0; j < 4; j++) {
                bf16x8 bfr = *(const bf16x8*)(Kt + cur + ch * 2048 + (j * 16 + l15) * 32 + quad * 8);
                sacc[j] = __builtin_amdgcn_mfma_f32_16x16x32_bf16(a, bfr, sacc[j], 0, 0, 0);
            }
        }
        // p = exp2(s); accumulate per-lane row-sum partials; store P to LDS
        #pragma unroll
        for (int r = 0; r < 4; r++) {
            int t = w * 16 + quad * 4 + r;
            #pragma unroll
            for (int j = 0; j < 4; j++) {
                float p = __builtin_amdgcn_exp2f(sacc[j][r]);
                lpart[r] += p;
                Ps[t * 72 + j * 16 + l15] = (__bf16)p;
            }
        }
        // O^T[t][c] += P V^T  (Ps written/read by same wave)
        #pragma unroll
        for (int ch = 0; ch < 2; ch++) {
            bf16x8 a = *(const bf16x8*)(Ps + (w * 16 + l15) * 72 + ch * 32 + quad * 8);
            #pragma unroll
            for (int ci = 0; ci < 4; ci++) {
                bf16x8 bfr = *(const bf16x8*)(Vt + cur + ch * 2048 + (ci * 16 + l15) * 32 + quad * 8);
                Oacc[ci] = __builtin_amdgcn_mfma_f32_16x16x32_bf16(a, bfr, Oacc[ci], 0, 0, 0);
            }
        }
    }
    const int b = bh >> 3, hh = bh & 7;
    #pragma unroll
    for (int r = 0; r < 4; r++) {
        float sum = lpart[r];
        sum += __shfl_xor(sum, 1);
        sum += __shfl_xor(sum, 2);
        sum += __shfl_xor(sum, 4);
        sum += __shfl_xor(sum, 8);
        float inv = 1.f / sum;
        int t = w * 16 + quad * 4 + r;
        size_t base = ((size_t)(b * NHW + t0 + t)) * NC + hh * 64;
        #pragma unroll
        for (int ci = 0; ci < 4; ci++)
            aT[base + ci * 16 + l15] = (__bf16)(Oacc[ci][r] * inv);
    }
}

// ---------------- final: out = x + GN2(proj) ----------------
__global__ __launch_bounds__(256) void final_k(const float* __restrict__ x,
                                               const float* __restrict__ p,
                                               const float* __restrict__ mu,
                                               const float* __restrict__ rinv,
                                               const float* __restrict__ sc,
                                               const float* __restrict__ bi,
                                               float* __restrict__ out) {
    const int i4 = blockIdx.x * 256 + threadIdx.x;
    const int c  = (i4 >> 8) & (NC - 1);
    const int b  = i4 >> 17;
    const int grp = b * NG + (c >> 4);
    const float m = mu[grp], r = rinv[grp];
    const float a = sc[c] * r;
    const float d = bi[c] - m * a;
    float4 xv = ((const float4*)x)[i4];
    float4 pv = ((const float4*)p)[i4];
    float4 o = make_float4(xv.x + pv.x * a + d, xv.y + pv.y * a + d,
                           xv.z + pv.z * a + d, xv.w + pv.w * a + d);
    ((float4*)out)[i4] = o;
}

extern "C" void kernel_launch(void* const* d_in, const int* in_sizes, int n_in,
                              void* d_out, int out_size, void* d_ws, size_t ws_size,
                              hipStream_t stream) {
    const float* x      = (const float*)d_in[0];
    const float* gn1_s  = (const float*)d_in[1];
    const float* gn1_b  = (const float*)d_in[2];
    const float* w_qkv  = (const float*)d_in[3];
    const float* b_qkv  = (const float*)d_in[4];
    const float* w_proj = (const float*)d_in[5];
    const float* b_proj = (const float*)d_in[6];
    const float* gn2_s  = (const float*)d_in[7];
    const float* gn2_b  = (const float*)d_in[8];
    float* out = (float*)d_out;

    char* p = (char*)d_ws;
    __bf16* hnT  = (__bf16*)p;            p += (size_t)8 * 1024 * 512 * 2;   // 8 MB
    __bf16* qT   = (__bf16*)p;            p += (size_t)64 * 1024 * 64 * 2;   // 8 MB
    __bf16* kT   = (__bf16*)p;            p += (size_t)64 * 1024 * 64 * 2;   // 8 MB
    __bf16* vB   = (__bf16*)p;            p += (size_t)64 * 64 * 1024 * 2;   // 8 MB
    __bf16* aT   = (__bf16*)p;            p += (size_t)8 * 1024 * 512 * 2;   // 8 MB
    float*  proj = (float*)p;             p += (size_t)8 * 512 * 1024 * 4;   // 16 MB
    __bf16* wq   = (__bf16*)p;            p += (size_t)QKV_C * NC * 2;       // 1.5 MB
    __bf16* wp   = (__bf16*)p;            p += (size_t)NC * NC * 2;          // 0.5 MB
    float*  mu1  = (float*)p;             p += 256 * 4;
    float*  ri1  = (float*)p;             p += 256 * 4;
    float*  mu2  = (float*)p;             p += 256 * 4;
    float*  ri2  = (float*)p;             p += 256 * 4;

    gn_stats_k<<<256, 256, 0, stream>>>(x, mu1, ri1);
    cvt2_k<<<(QKV_C * NC + NC * NC) / 1024, 256, 0, stream>>>(
        w_qkv, wq, w_proj, wp, QKV_C * NC / 4);
    gn_apply_t_k<<<dim3(16, 8, 8), 256, 0, stream>>>(x, mu1, ri1, gn1_s, gn1_b, hnT);

    qkv_gemm_k<<<dim3(12, 8, 8), 256, 0, stream>>>(wq, hnT, b_qkv, qT, kT, vB);

    attn_k<<<dim3(64, 16), 256, 0, stream>>>(qT, kT, vB, aT);

    proj_gemm_k<<<dim3(4, 8, 8), 256, 0, stream>>>(wp, aT, b_proj, proj);

    gn_stats_k<<<256, 256, 0, stream>>>(proj, mu2, ri2);
    final_k<<<4096, 256, 0, stream>>>(x, proj, mu2, ri2, gn2_s, gn2_b, out);
}

// Round 5
// 193.489 us; speedup vs baseline: 4.1808x; 1.0113x over previous
//
#include <hip/hip_runtime.h>
#include <math.h>

#define NB 8
#define NC 512
#define NHW 1024
#define NG 32
#define CPG 16
#define QKV_C 1536
#define EPS 1e-5f
#define QSCALE 0.18033688011112042f   // 0.125 * log2(e)

typedef float  f32x4  __attribute__((ext_vector_type(4)));
typedef __bf16 bf16x8 __attribute__((ext_vector_type(8)));
typedef __bf16 bf16x4 __attribute__((ext_vector_type(4)));
typedef short  s16x4  __attribute__((ext_vector_type(4)));

__device__ __forceinline__ void gload_lds16(const void* g, void* l) {
    __builtin_amdgcn_global_load_lds(
        (const __attribute__((address_space(1))) void*)g,
        (__attribute__((address_space(3))) void*)l, 16, 0, 0);
}

// Drain this wave's outstanding global_load_lds DMA (vmcnt) before a
// __syncthreads() that publishes DMA-written LDS (R3 divergence fix).
__device__ __forceinline__ void dma_drain() {
    asm volatile("s_waitcnt vmcnt(0)" ::: "memory");
}

// 16x16x16 bf16 MFMA (K=16): A/B = 4 bf16 (2 VGPRs), C/D = 4 f32.
__device__ __forceinline__ f32x4 mfma16(bf16x4 a, bf16x4 b, f32x4 c) {
#if __has_builtin(__builtin_amdgcn_mfma_f32_16x16x16bf16_1k)
    return __builtin_amdgcn_mfma_f32_16x16x16bf16_1k(
        __builtin_bit_cast(s16x4, a), __builtin_bit_cast(s16x4, b), c, 0, 0, 0);
#else
    f32x4 d;
    asm volatile("v_mfma_f32_16x16x16_bf16 %0, %1, %2, %3"
                 : "=v"(d) : "v"(a), "v"(b), "v"(c));
    return d;
#endif
}

// ---------------- prep: GN1 stats (blocks 0..255) + weight cvt (256..1279) + zero gstat ----
__global__ __launch_bounds__(256) void prep_k(const float* __restrict__ x,
                                              float* __restrict__ mu,
                                              float* __restrict__ rinv,
                                              const float* __restrict__ w1,
                                              __bf16* __restrict__ d1,
                                              const float* __restrict__ w2,
                                              __bf16* __restrict__ d2,
                                              float* __restrict__ gstat) {
    const int bi = blockIdx.x;
    if (bi < 256) {
        const int grp = bi;
        const float4* p4 = (const float4*)(x + (size_t)grp * (CPG * NHW));
        float s = 0.f, s2 = 0.f;
        for (int i = threadIdx.x; i < CPG * NHW / 4; i += 256) {
            float4 v = p4[i];
            s  += v.x + v.y + v.z + v.w;
            s2 += v.x * v.x + v.y * v.y + v.z * v.z + v.w * v.w;
        }
        for (int off = 32; off > 0; off >>= 1) {
            s  += __shfl_down(s, off);
            s2 += __shfl_down(s2, off);
        }
        __shared__ float ls[4], ls2[4];
        const int wv = threadIdx.x >> 6;
        if ((threadIdx.x & 63) == 0) { ls[wv] = s; ls2[wv] = s2; }
        __syncthreads();
        if (threadIdx.x == 0) {
            float S = ls[0] + ls[1] + ls[2] + ls[3];
            float S2 = ls2[0] + ls2[1] + ls2[2] + ls2[3];
            const float inv = 1.f / (float)(CPG * NHW);
            float m = S * inv;
            float var = S2 * inv - m * m;
            mu[grp] = m;
            rinv[grp] = rsqrtf(var + EPS);
        }
        if (bi == 0 && threadIdx.x < 256) {
            gstat[threadIdx.x] = 0.f;
            gstat[threadIdx.x + 256] = 0.f;
        }
    } else {
        const int n1_4 = QKV_C * NC / 4;   // 196608
        const int i = (bi - 256) * 256 + threadIdx.x;
        const float4* s = (i < n1_4) ? (const float4*)w1 + i
                                     : (const float4*)w2 + (i - n1_4);
        bf16x4* d = (i < n1_4) ? (bf16x4*)d1 + i : (bf16x4*)d2 + (i - n1_4);
        float4 v = *s;
        bf16x4 o;
        o[0] = (__bf16)v.x; o[1] = (__bf16)v.y; o[2] = (__bf16)v.z; o[3] = (__bf16)v.w;
        *d = o;
    }
}

// ---------------- GN1 apply + transpose: hnT[b][n][c] bf16 ----------------
__global__ __launch_bounds__(256) void gn_apply_t_k(const float* __restrict__ x,
                                                    const float* __restrict__ mu,
                                                    const float* __restrict__ rinv,
                                                    const float* __restrict__ sc,
                                                    const float* __restrict__ bi,
                                                    __bf16* __restrict__ hnT) {
    __shared__ float T[64][65];
    const int tid = threadIdx.x;
    const int nb = blockIdx.x * 64, cb = blockIdx.y * 64, b = blockIdx.z;
    const int col = (tid & 15) * 4;
    const int rb = tid >> 4;
    #pragma unroll
    for (int rr = 0; rr < 4; rr++) {
        int cl = rr * 16 + rb;
        int c = cb + cl;
        int grp = b * NG + (c >> 4);
        float a = sc[c] * rinv[grp];
        float d = bi[c] - mu[grp] * a;
        float4 v4 = *(const float4*)&x[((size_t)(b * NC + c)) * NHW + nb + col];
        T[cl][col + 0] = v4.x * a + d;
        T[cl][col + 1] = v4.y * a + d;
        T[cl][col + 2] = v4.z * a + d;
        T[cl][col + 3] = v4.w * a + d;
    }
    __syncthreads();
    const int nl = tid >> 2;
    const int c0 = (tid & 3) * 16;
    bf16x8 o0, o1;
    #pragma unroll
    for (int i = 0; i < 8; i++) o0[i] = (__bf16)T[c0 + i][nl];
    #pragma unroll
    for (int i = 0; i < 8; i++) o1[i] = (__bf16)T[c0 + 8 + i][nl];
    __bf16* dst = hnT + ((size_t)(b * NHW + nb + nl)) * NC + cb + c0;
    *(bf16x8*)dst = o0;
    *(bf16x8*)(dst + 8) = o1;
}

// ---------------- MFMA GEMM core: 128x128 tile, BK=32, ping-pong LDS ----------------
__device__ __forceinline__ void mm_stage(const __bf16* __restrict__ W,
                                         const __bf16* __restrict__ Bm,
                                         int K, int m0, int n0, int k0,
                                         __bf16* As, __bf16* Bs) {
    const int tid = threadIdx.x;
    const int w = tid >> 6, lane = tid & 63;
    const int lr = lane >> 2, lk = (lane & 3) * 8;
    #pragma unroll
    for (int i = 0; i < 2; i++) {
        int rb = (w * 2 + i) * 16;
        gload_lds16(W  + (size_t)(m0 + rb + lr) * K + k0 + lk, As + rb * 32);
        gload_lds16(Bm + (size_t)(n0 + rb + lr) * K + k0 + lk, Bs + rb * 32);
    }
}

__device__ __forceinline__ void mm_core(const __bf16* __restrict__ W,
                                        const __bf16* __restrict__ Bm,
                                        int K, int m0, int n0,
                                        __bf16* As, __bf16* Bs,
                                        f32x4 (&acc)[4][4]) {
    const int tid = threadIdx.x;
    const int w = tid >> 6, lane = tid & 63;
    const int l15 = lane & 15, quad = lane >> 4;
    const int wm = (w & 1) * 64, wn = (w >> 1) * 64;
    const int nk = K >> 5;
    mm_stage(W, Bm, K, m0, n0, 0, As, Bs);
    for (int it = 0; it < nk; it++) {
        const int cur = (it & 1) * 4096;
        dma_drain();
        __syncthreads();
        if (it + 1 < nk)
            mm_stage(W, Bm, K, m0, n0, (it + 1) * 32, As + (4096 - cur), Bs + (4096 - cur));
        bf16x8 af[4], bfv[4];
        #pragma unroll
        for (int mi = 0; mi < 4; mi++)
            af[mi] = *(const bf16x8*)(As + cur + (wm + mi * 16 + l15) * 32 + quad * 8);
        #pragma unroll
        for (int ni = 0; ni < 4; ni++)
            bfv[ni] = *(const bf16x8*)(Bs + cur + (wn + ni * 16 + l15) * 32 + quad * 8);
        #pragma unroll
        for (int mi = 0; mi < 4; mi++)
            #pragma unroll
            for (int ni = 0; ni < 4; ni++)
                acc[mi][ni] = __builtin_amdgcn_mfma_f32_16x16x32_bf16(
                    af[mi], bfv[ni], acc[mi][ni], 0, 0, 0);
    }
}

// ---------------- QKV GEMM: out -> qT[bh][n][64] (pre-scaled), kT[bh][n][64], v[bh][c][n] ----
__global__ __launch_bounds__(256) void qkv_gemm_k(const __bf16* __restrict__ W,
                                                  const __bf16* __restrict__ hnT,
                                                  const float* __restrict__ bias,
                                                  __bf16* __restrict__ qT,
                                                  __bf16* __restrict__ kT,
                                                  __bf16* __restrict__ v) {
    __shared__ __bf16 As[2 * 128 * 32];
    __shared__ __bf16 Bs[2 * 128 * 32];
    const int m0 = blockIdx.x * 128, n0 = blockIdx.y * 128, b = blockIdx.z;
    f32x4 acc[4][4] = {};
    mm_core(W, hnT + (size_t)b * NHW * NC, NC, m0, n0, As, Bs, acc);
    const int tid = threadIdx.x;
    const int w = tid >> 6, lane = tid & 63;
    const int l15 = lane & 15, quad = lane >> 4;
    const int wm = (w & 1) * 64, wn = (w >> 1) * 64;
    #pragma unroll
    for (int mi = 0; mi < 4; mi++) {
        #pragma unroll
        for (int r = 0; r < 4; r++) {
            int m = m0 + wm + mi * 16 + quad * 4 + r;
            float bb = bias[m];
            int h = m / 192;
            int rr = m - h * 192;
            int bh = b * 8 + h;
            #pragma unroll
            for (int ni = 0; ni < 4; ni++) {
                int n = n0 + wn + ni * 16 + l15;
                float val = acc[mi][ni][r] + bb;
                if (rr < 64) {
                    qT[((size_t)bh << 16) + n * 64 + rr] = (__bf16)(val * QSCALE);
                } else if (rr < 128) {
                    kT[((size_t)bh << 16) + n * 64 + (rr - 64)] = (__bf16)val;
                } else {
                    v[((size_t)(bh * 64 + rr - 128)) * NHW + n] = (__bf16)val;
                }
            }
        }
    }
}

// ---------------- proj GEMM: projb[b][m][n] bf16 + GN2 partial sums via atomics ----
__global__ __launch_bounds__(256) void proj_gemm_k(const __bf16* __restrict__ W,
                                                   const __bf16* __restrict__ aT,
                                                   const float* __restrict__ bias,
                                                   __bf16* __restrict__ projb,
                                                   float* __restrict__ gstat) {
    __shared__ __bf16 As[2 * 128 * 32];
    __shared__ __bf16 Bs[2 * 128 * 32];
    const int m0 = blockIdx.x * 128, n0 = blockIdx.y * 128, b = blockIdx.z;
    f32x4 acc[4][4] = {};
    mm_core(W, aT + (size_t)b * NHW * NC, NC, m0, n0, As, Bs, acc);
    const int tid = threadIdx.x;
    const int w = tid >> 6, lane = tid & 63;
    const int l15 = lane & 15, quad = lane >> 4;
    const int wm = (w & 1) * 64, wn = (w >> 1) * 64;
    float bsum[4] = {}, bsq[4] = {};
    #pragma unroll
    for (int mi = 0; mi < 4; mi++) {
        #pragma unroll
        for (int r = 0; r < 4; r++) {
            int m = m0 + wm + mi * 16 + quad * 4 + r;
            float bb = bias[m];
            #pragma unroll
            for (int ni = 0; ni < 4; ni++) {
                int n = n0 + wn + ni * 16 + l15;
                float val = acc[mi][ni][r] + bb;
                projb[((size_t)(b * NC + m)) * NHW + n] = (__bf16)val;
                bsum[mi] += val;
                bsq[mi] += val * val;
            }
        }
    }
    #pragma unroll
    for (int mi = 0; mi < 4; mi++) {
        float s = bsum[mi], q = bsq[mi];
        #pragma unroll
        for (int off = 1; off < 64; off <<= 1) {
            s += __shfl_xor(s, off);
            q += __shfl_xor(q, off);
        }
        if (lane == 0) {
            int grp = b * NG + ((m0 + wm) >> 4) + mi;
            atomicAdd(&gstat[grp], s);
            atomicAdd(&gstat[256 + grp], q);
        }
    }
}

// ---------------- MFMA flash attention: S^T trick, P in registers ----------------
// grid (64 bh, 8 q-tiles of 128), 256 threads. Wave w owns t in [t0+32w, t0+32w+32).
// qT (pre-scaled): [bh][t][64]; kT: [bh][s][64]; v: [bh][c][s]; out aT: [b][t][512].
// S^T = K*Q^T via mfma(A=Kfrag, B=Qfrag) -> C-layout (row=s, col=t) == A-frag of P
// for the K=16 PV mfma. exp2 fully in registers; no P LDS round-trip.
__global__ __launch_bounds__(256) void attn_k(const __bf16* __restrict__ qT,
                                              const __bf16* __restrict__ kT,
                                              const __bf16* __restrict__ vv,
                                              __bf16* __restrict__ aT) {
    __shared__ __bf16 Kt[2 * 4096];   // [buf][ch][s][32] (lane-linear DMA layout)
    __shared__ __bf16 Vt[2 * 4096];   // [buf][s-chunk][c][32]
    const int tid = threadIdx.x;
    const int w = tid >> 6, lane = tid & 63;
    const int l15 = lane & 15, quad = lane >> 4;
    const int lr = lane >> 2, lk = (lane & 3) * 8;
    const int bh = blockIdx.x, t0 = blockIdx.y * 128;
    const __bf16* qb = qT + ((size_t)bh << 16);
    const __bf16* kb = kT + ((size_t)bh << 16);
    const __bf16* vb = vv + ((size_t)bh << 6) * NHW;

    // Q fragments in registers: B[n=t][k=c] layout, t = t0+w*32+tb*16+l15
    bf16x8 qfr[2][2];
    #pragma unroll
    for (int tb = 0; tb < 2; tb++)
        #pragma unroll
        for (int ch = 0; ch < 2; ch++)
            qfr[tb][ch] = *(const bf16x8*)(qb + (size_t)(t0 + w * 32 + tb * 16 + l15) * 64
                                           + ch * 32 + quad * 8);
    // stage K/V tile 0 into buffer 0
    #pragma unroll
    for (int i = 0; i < 4; i++) {
        int inst = w * 4 + i;
        if (inst < 8) {
            int ch = inst >> 2, sb = (inst & 3) * 16;
            gload_lds16(kb + (size_t)(sb + lr) * 64 + ch * 32 + lk,
                        Kt + ch * 2048 + sb * 32);
        } else {
            int i2 = inst - 8;
            int ch = i2 >> 2, cb = (i2 & 3) * 16;
            gload_lds16(vb + (size_t)(cb + lr) * NHW + ch * 32 + lk,
                        Vt + ch * 2048 + cb * 32);
        }
    }
    float lp[2] = {0.f, 0.f};
    f32x4 Oacc[2][4] = {};

    for (int it = 0; it < 16; it++) {
        const int cur = (it & 1) * 4096;
        const int nxt = 4096 - cur;
        dma_drain();
        __syncthreads();
        if (it + 1 < 16) {
            const int s0 = (it + 1) * 64;
            #pragma unroll
            for (int i = 0; i < 4; i++) {
                int inst = w * 4 + i;
                if (inst < 8) {
                    int ch = inst >> 2, sb = (inst & 3) * 16;
                    gload_lds16(kb + (size_t)(s0 + sb + lr) * 64 + ch * 32 + lk,
                                Kt + nxt + ch * 2048 + sb * 32);
                } else {
                    int i2 = inst - 8;
                    int ch = i2 >> 2, cb = (i2 & 3) * 16;
                    gload_lds16(vb + (size_t)(cb + lr) * NHW + s0 + ch * 32 + lk,
                                Vt + nxt + ch * 2048 + cb * 32);
                }
            }
        }
        // S^T tiles: sacc[tb][j] covers s in [16j,16j+16), t-block tb
        f32x4 sacc[2][4] = {};
        #pragma unroll
        for (int ch = 0; ch < 2; ch++)
            #pragma unroll
            for (int j = 0; j < 4; j++) {
                bf16x8 kfr = *(const bf16x8*)(Kt + cur + ch * 2048
                                              + (j * 16 + l15) * 32 + quad * 8);
                sacc[0][j] = __builtin_amdgcn_mfma_f32_16x16x32_bf16(
                    kfr, qfr[0][ch], sacc[0][j], 0, 0, 0);
                sacc[1][j] = __builtin_amdgcn_mfma_f32_16x16x32_bf16(
                    kfr, qfr[1][ch], sacc[1][j], 0, 0, 0);
            }
        // P = exp2(S^T) in registers; pack to A-frags for K=16 PV mfma
        bf16x4 pf[2][4];
        #pragma unroll
        for (int tb = 0; tb < 2; tb++)
            #pragma unroll
            for (int j = 0; j < 4; j++) {
                bf16x4 pk;
                #pragma unroll
                for (int r = 0; r < 4; r++) {
                    float pv = __builtin_amdgcn_exp2f(sacc[tb][j][r]);
                    lp[tb] += pv;
                    pk[r] = (__bf16)pv;
                }
                pf[tb][j] = pk;
            }
        // O^T[t][c] += P[t][s] * V[c][s]
        #pragma unroll
        for (int jt = 0; jt < 4; jt++) {
            int sg = jt * 16 + quad * 4;
            const __bf16* vbase = Vt + cur + (sg >> 5) * 2048 + (sg & 31);
            #pragma unroll
            for (int ci = 0; ci < 4; ci++) {
                bf16x4 vfr = *(const bf16x4*)(vbase + (ci * 16 + l15) * 32);
                Oacc[0][ci] = mfma16(pf[0][jt], vfr, Oacc[0][ci]);
                Oacc[1][ci] = mfma16(pf[1][jt], vfr, Oacc[1][ci]);
            }
        }
    }
    const int b = bh >> 3, hh = bh & 7;
    #pragma unroll
    for (int tb = 0; tb < 2; tb++) {
        float s = lp[tb];
        s += __shfl_xor(s, 16);
        s += __shfl_xor(s, 32);     // every lane: row-sum for t_local = l15
        #pragma unroll
        for (int r = 0; r < 4; r++) {
            float inv = 1.f / __shfl(s, quad * 4 + r);
            int t = t0 + w * 32 + tb * 16 + quad * 4 + r;
            size_t base = ((size_t)(b * NHW + t)) * NC + hh * 64;
            #pragma unroll
            for (int ci = 0; ci < 4; ci++)
                aT[base + ci * 16 + l15] = (__bf16)(Oacc[tb][ci][r] * inv);
        }
    }
}

// ---------------- final: out = x + GN2(projb), stats from gstat sums ----------------
__global__ __launch_bounds__(256) void final_k(const float* __restrict__ x,
                                               const __bf16* __restrict__ pb,
                                               const float* __restrict__ gstat,
                                               const float* __restrict__ sc,
                                               const float* __restrict__ bi,
                                               float* __restrict__ out) {
    const int i4 = blockIdx.x * 256 + threadIdx.x;
    const int c  = (i4 >> 8) & (NC - 1);
    const int b  = i4 >> 17;
    const int grp = b * NG + (c >> 4);
    const float inv = 1.f / (float)(CPG * NHW);
    const float m = gstat[grp] * inv;
    const float var = gstat[256 + grp] * inv - m * m;
    const float r = rsqrtf(var + EPS);
    const float a = sc[c] * r;
    const float d = bi[c] - m * a;
    float4 xv = ((const float4*)x)[i4];
    bf16x4 pv = ((const bf16x4*)pb)[i4];
    float4 o = make_float4(xv.x + (float)pv[0] * a + d, xv.y + (float)pv[1] * a + d,
                           xv.z + (float)pv[2] * a + d, xv.w + (float)pv[3] * a + d);
    ((float4*)out)[i4] = o;
}

extern "C" void kernel_launch(void* const* d_in, const int* in_sizes, int n_in,
                              void* d_out, int out_size, void* d_ws, size_t ws_size,
                              hipStream_t stream) {
    const float* x      = (const float*)d_in[0];
    const float* gn1_s  = (const float*)d_in[1];
    const float* gn1_b  = (const float*)d_in[2];
    const float* w_qkv  = (const float*)d_in[3];
    const float* b_qkv  = (const float*)d_in[4];
    const float* w_proj = (const float*)d_in[5];
    const float* b_proj = (const float*)d_in[6];
    const float* gn2_s  = (const float*)d_in[7];
    const float* gn2_b  = (const float*)d_in[8];
    float* out = (float*)d_out;

    char* p = (char*)d_ws;
    __bf16* hnT   = (__bf16*)p;           p += (size_t)8 * 1024 * 512 * 2;   // 8 MB
    __bf16* qT    = (__bf16*)p;           p += (size_t)64 * 1024 * 64 * 2;   // 8 MB
    __bf16* kT    = (__bf16*)p;           p += (size_t)64 * 1024 * 64 * 2;   // 8 MB
    __bf16* vB    = (__bf16*)p;           p += (size_t)64 * 64 * 1024 * 2;   // 8 MB
    __bf16* aT    = (__bf16*)p;           p += (size_t)8 * 1024 * 512 * 2;   // 8 MB
    __bf16* projb = (__bf16*)p;           p += (size_t)8 * 512 * 1024 * 2;   // 8 MB
    __bf16* wq    = (__bf16*)p;           p += (size_t)QKV_C * NC * 2;       // 1.5 MB
    __bf16* wp    = (__bf16*)p;           p += (size_t)NC * NC * 2;          // 0.5 MB
    float*  mu1   = (float*)p;            p += 256 * 4;
    float*  ri1   = (float*)p;            p += 256 * 4;
    float*  gstat = (float*)p;            p += 512 * 4;   // [0:256) sum, [256:512) sumsq

    // blocks: 256 stats + 1024 cvt
    prep_k<<<1280, 256, 0, stream>>>(x, mu1, ri1, w_qkv, wq, w_proj, wp, gstat);
    gn_apply_t_k<<<dim3(16, 8, 8), 256, 0, stream>>>(x, mu1, ri1, gn1_s, gn1_b, hnT);

    qkv_gemm_k<<<dim3(12, 8, 8), 256, 0, stream>>>(wq, hnT, b_qkv, qT, kT, vB);

    attn_k<<<dim3(64, 8), 256, 0, stream>>>(qT, kT, vB, aT);

    proj_gemm_k<<<dim3(4, 8, 8), 256, 0, stream>>>(wp, aT, b_proj, projb, gstat);

    final_k<<<4096, 256, 0, stream>>>(x, projb, gstat, gn2_s, gn2_b, out);
}

// Round 6
// 181.363 us; speedup vs baseline: 4.4603x; 1.0669x over previous
//
#include <hip/hip_runtime.h>
#include <math.h>

#define NB 8
#define NC 512
#define NHW 1024
#define NG 32
#define CPG 16
#define QKV_C 1536
#define EPS 1e-5f
#define QSCALE 0.18033688011112042f   // 0.125 * log2(e)

typedef float  f32x4  __attribute__((ext_vector_type(4)));
typedef __bf16 bf16x8 __attribute__((ext_vector_type(8)));
typedef __bf16 bf16x4 __attribute__((ext_vector_type(4)));
typedef short  s16x4  __attribute__((ext_vector_type(4)));

__device__ __forceinline__ void gload_lds16(const void* g, void* l) {
    __builtin_amdgcn_global_load_lds(
        (const __attribute__((address_space(1))) void*)g,
        (__attribute__((address_space(3))) void*)l, 16, 0, 0);
}

// Drain this wave's outstanding global_load_lds DMA (vmcnt) before a
// __syncthreads() that publishes DMA-written LDS (R3 divergence fix).
__device__ __forceinline__ void dma_drain() {
    asm volatile("s_waitcnt vmcnt(0)" ::: "memory");
}

// 16x16x16 bf16 MFMA (K=16): A/B = 4 bf16 (2 VGPRs), C/D = 4 f32.
__device__ __forceinline__ f32x4 mfma16(bf16x4 a, bf16x4 b, f32x4 c) {
#if __has_builtin(__builtin_amdgcn_mfma_f32_16x16x16bf16_1k)
    return __builtin_amdgcn_mfma_f32_16x16x16bf16_1k(
        __builtin_bit_cast(s16x4, a), __builtin_bit_cast(s16x4, b), c, 0, 0, 0);
#else
    f32x4 d;
    asm volatile("v_mfma_f32_16x16x16_bf16 %0, %1, %2, %3"
                 : "=v"(d) : "v"(a), "v"(b), "v"(c));
    return d;
#endif
}

// ---------------- prep: GN1 stats (blocks 0..255) + weight cvt (256..1279) + zero gstat ----
__global__ __launch_bounds__(256) void prep_k(const float* __restrict__ x,
                                              float* __restrict__ mu,
                                              float* __restrict__ rinv,
                                              const float* __restrict__ w1,
                                              __bf16* __restrict__ d1,
                                              const float* __restrict__ w2,
                                              __bf16* __restrict__ d2,
                                              float* __restrict__ gstat) {
    const int bi = blockIdx.x;
    if (bi < 256) {
        const int grp = bi;
        const float4* p4 = (const float4*)(x + (size_t)grp * (CPG * NHW));
        float s = 0.f, s2 = 0.f;
        for (int i = threadIdx.x; i < CPG * NHW / 4; i += 256) {
            float4 v = p4[i];
            s  += v.x + v.y + v.z + v.w;
            s2 += v.x * v.x + v.y * v.y + v.z * v.z + v.w * v.w;
        }
        for (int off = 32; off > 0; off >>= 1) {
            s  += __shfl_down(s, off);
            s2 += __shfl_down(s2, off);
        }
        __shared__ float ls[4], ls2[4];
        const int wv = threadIdx.x >> 6;
        if ((threadIdx.x & 63) == 0) { ls[wv] = s; ls2[wv] = s2; }
        __syncthreads();
        if (threadIdx.x == 0) {
            float S = ls[0] + ls[1] + ls[2] + ls[3];
            float S2 = ls2[0] + ls2[1] + ls2[2] + ls2[3];
            const float inv = 1.f / (float)(CPG * NHW);
            float m = S * inv;
            float var = S2 * inv - m * m;
            mu[grp] = m;
            rinv[grp] = rsqrtf(var + EPS);
        }
        if (bi == 0 && threadIdx.x < 256) {
            gstat[threadIdx.x] = 0.f;
            gstat[threadIdx.x + 256] = 0.f;
        }
    } else {
        const int n1_4 = QKV_C * NC / 4;   // 196608
        const int i = (bi - 256) * 256 + threadIdx.x;
        const float4* s = (i < n1_4) ? (const float4*)w1 + i
                                     : (const float4*)w2 + (i - n1_4);
        bf16x4* d = (i < n1_4) ? (bf16x4*)d1 + i : (bf16x4*)d2 + (i - n1_4);
        float4 v = *s;
        bf16x4 o;
        o[0] = (__bf16)v.x; o[1] = (__bf16)v.y; o[2] = (__bf16)v.z; o[3] = (__bf16)v.w;
        *d = o;
    }
}

// ---------------- GN1 apply + transpose: hnT[b][n][c] bf16 ----------------
__global__ __launch_bounds__(256) void gn_apply_t_k(const float* __restrict__ x,
                                                    const float* __restrict__ mu,
                                                    const float* __restrict__ rinv,
                                                    const float* __restrict__ sc,
                                                    const float* __restrict__ bi,
                                                    __bf16* __restrict__ hnT) {
    __shared__ float T[64][65];
    const int tid = threadIdx.x;
    const int nb = blockIdx.x * 64, cb = blockIdx.y * 64, b = blockIdx.z;
    const int col = (tid & 15) * 4;
    const int rb = tid >> 4;
    #pragma unroll
    for (int rr = 0; rr < 4; rr++) {
        int cl = rr * 16 + rb;
        int c = cb + cl;
        int grp = b * NG + (c >> 4);
        float a = sc[c] * rinv[grp];
        float d = bi[c] - mu[grp] * a;
        float4 v4 = *(const float4*)&x[((size_t)(b * NC + c)) * NHW + nb + col];
        T[cl][col + 0] = v4.x * a + d;
        T[cl][col + 1] = v4.y * a + d;
        T[cl][col + 2] = v4.z * a + d;
        T[cl][col + 3] = v4.w * a + d;
    }
    __syncthreads();
    const int nl = tid >> 2;
    const int c0 = (tid & 3) * 16;
    bf16x8 o0, o1;
    #pragma unroll
    for (int i = 0; i < 8; i++) o0[i] = (__bf16)T[c0 + i][nl];
    #pragma unroll
    for (int i = 0; i < 8; i++) o1[i] = (__bf16)T[c0 + 8 + i][nl];
    __bf16* dst = hnT + ((size_t)(b * NHW + nb + nl)) * NC + cb + c0;
    *(bf16x8*)dst = o0;
    *(bf16x8*)(dst + 8) = o1;
}

// ---------------- MFMA GEMM core: 128x128 tile, BK=32, ping-pong LDS ----------------
__device__ __forceinline__ void mm_stage(const __bf16* __restrict__ W,
                                         const __bf16* __restrict__ Bm,
                                         int K, int m0, int n0, int k0,
                                         __bf16* As, __bf16* Bs) {
    const int tid = threadIdx.x;
    const int w = tid >> 6, lane = tid & 63;
    const int lr = lane >> 2, lk = (lane & 3) * 8;
    #pragma unroll
    for (int i = 0; i < 2; i++) {
        int rb = (w * 2 + i) * 16;
        gload_lds16(W  + (size_t)(m0 + rb + lr) * K + k0 + lk, As + rb * 32);
        gload_lds16(Bm + (size_t)(n0 + rb + lr) * K + k0 + lk, Bs + rb * 32);
    }
}

__device__ __forceinline__ void mm_core(const __bf16* __restrict__ W,
                                        const __bf16* __restrict__ Bm,
                                        int K, int m0, int n0,
                                        __bf16* As, __bf16* Bs,
                                        f32x4 (&acc)[4][4]) {
    const int tid = threadIdx.x;
    const int w = tid >> 6, lane = tid & 63;
    const int l15 = lane & 15, quad = lane >> 4;
    const int wm = (w & 1) * 64, wn = (w >> 1) * 64;
    const int nk = K >> 5;
    mm_stage(W, Bm, K, m0, n0, 0, As, Bs);
    for (int it = 0; it < nk; it++) {
        const int cur = (it & 1) * 4096;
        dma_drain();
        __syncthreads();
        if (it + 1 < nk)
            mm_stage(W, Bm, K, m0, n0, (it + 1) * 32, As + (4096 - cur), Bs + (4096 - cur));
        bf16x8 af[4], bfv[4];
        #pragma unroll
        for (int mi = 0; mi < 4; mi++)
            af[mi] = *(const bf16x8*)(As + cur + (wm + mi * 16 + l15) * 32 + quad * 8);
        #pragma unroll
        for (int ni = 0; ni < 4; ni++)
            bfv[ni] = *(const bf16x8*)(Bs + cur + (wn + ni * 16 + l15) * 32 + quad * 8);
        #pragma unroll
        for (int mi = 0; mi < 4; mi++)
            #pragma unroll
            for (int ni = 0; ni < 4; ni++)
                acc[mi][ni] = __builtin_amdgcn_mfma_f32_16x16x32_bf16(
                    af[mi], bfv[ni], acc[mi][ni], 0, 0, 0);
    }
}

// ---------------- QKV GEMM: out -> qT[bh][n][64] (pre-scaled), kT[bh][n][64], v[bh][c][n] ----
__global__ __launch_bounds__(256) void qkv_gemm_k(const __bf16* __restrict__ W,
                                                  const __bf16* __restrict__ hnT,
                                                  const float* __restrict__ bias,
                                                  __bf16* __restrict__ qT,
                                                  __bf16* __restrict__ kT,
                                                  __bf16* __restrict__ v) {
    __shared__ __bf16 As[2 * 128 * 32];
    __shared__ __bf16 Bs[2 * 128 * 32];
    const int m0 = blockIdx.x * 128, n0 = blockIdx.y * 128, b = blockIdx.z;
    f32x4 acc[4][4] = {};
    mm_core(W, hnT + (size_t)b * NHW * NC, NC, m0, n0, As, Bs, acc);
    const int tid = threadIdx.x;
    const int w = tid >> 6, lane = tid & 63;
    const int l15 = lane & 15, quad = lane >> 4;
    const int wm = (w & 1) * 64, wn = (w >> 1) * 64;
    #pragma unroll
    for (int mi = 0; mi < 4; mi++) {
        #pragma unroll
        for (int r = 0; r < 4; r++) {
            int m = m0 + wm + mi * 16 + quad * 4 + r;
            float bb = bias[m];
            int h = m / 192;
            int rr = m - h * 192;
            int bh = b * 8 + h;
            #pragma unroll
            for (int ni = 0; ni < 4; ni++) {
                int n = n0 + wn + ni * 16 + l15;
                float val = acc[mi][ni][r] + bb;
                if (rr < 64) {
                    qT[((size_t)bh << 16) + n * 64 + rr] = (__bf16)(val * QSCALE);
                } else if (rr < 128) {
                    kT[((size_t)bh << 16) + n * 64 + (rr - 64)] = (__bf16)val;
                } else {
                    v[((size_t)(bh * 64 + rr - 128)) * NHW + n] = (__bf16)val;
                }
            }
        }
    }
}

// ---------------- proj GEMM: projb[b][m][n] bf16 + GN2 partial sums via atomics ----
__global__ __launch_bounds__(256) void proj_gemm_k(const __bf16* __restrict__ W,
                                                   const __bf16* __restrict__ aT,
                                                   const float* __restrict__ bias,
                                                   __bf16* __restrict__ projb,
                                                   float* __restrict__ gstat) {
    __shared__ __bf16 As[2 * 128 * 32];
    __shared__ __bf16 Bs[2 * 128 * 32];
    const int m0 = blockIdx.x * 128, n0 = blockIdx.y * 128, b = blockIdx.z;
    f32x4 acc[4][4] = {};
    mm_core(W, aT + (size_t)b * NHW * NC, NC, m0, n0, As, Bs, acc);
    const int tid = threadIdx.x;
    const int w = tid >> 6, lane = tid & 63;
    const int l15 = lane & 15, quad = lane >> 4;
    const int wm = (w & 1) * 64, wn = (w >> 1) * 64;
    float bsum[4] = {}, bsq[4] = {};
    #pragma unroll
    for (int mi = 0; mi < 4; mi++) {
        #pragma unroll
        for (int r = 0; r < 4; r++) {
            int m = m0 + wm + mi * 16 + quad * 4 + r;
            float bb = bias[m];
            #pragma unroll
            for (int ni = 0; ni < 4; ni++) {
                int n = n0 + wn + ni * 16 + l15;
                float val = acc[mi][ni][r] + bb;
                projb[((size_t)(b * NC + m)) * NHW + n] = (__bf16)val;
                bsum[mi] += val;
                bsq[mi] += val * val;
            }
        }
    }
    #pragma unroll
    for (int mi = 0; mi < 4; mi++) {
        float s = bsum[mi], q = bsq[mi];
        #pragma unroll
        for (int off = 1; off < 64; off <<= 1) {
            s += __shfl_xor(s, off);
            q += __shfl_xor(q, off);
        }
        if (lane == 0) {
            int grp = b * NG + ((m0 + wm) >> 4) + mi;
            atomicAdd(&gstat[grp], s);
            atomicAdd(&gstat[256 + grp], q);
        }
    }
}

// ---------------- MFMA flash attention: S^T trick, XOR-swizzled V ----------------
// grid (64 bh, 8 q-tiles of 128), 256 threads. Wave w owns t in [t0+32w, t0+32w+32).
// qT (pre-scaled): [bh][t][64]; kT: [bh][s][64]; v: [bh][c][s]; out aT: [b][t][512].
// V LDS layout [c][64] with 4-element chunk j stored at slot j ^ (c & 14):
//  - DMA-stageable (mask excludes bit0 -> 16B source spans stay contiguous)
//  - PV b64 frag read hits bank 2*((jt*4+quad)^(l15&14)): 4 addrs/bank = conflict-free
__global__ __launch_bounds__(256) void attn_k(const __bf16* __restrict__ qT,
                                              const __bf16* __restrict__ kT,
                                              const __bf16* __restrict__ vv,
                                              __bf16* __restrict__ aT) {
    __shared__ __bf16 Kt[2 * 4096];   // [buf][ch][s][32] (lane-linear DMA layout)
    __shared__ __bf16 Vt[2 * 4096];   // [buf][c][64] chunk-XOR swizzled
    const int tid = threadIdx.x;
    const int w = tid >> 6, lane = tid & 63;
    const int l15 = lane & 15, quad = lane >> 4;
    const int lr = lane >> 2, lk = (lane & 3) * 8;
    const int bh = blockIdx.x, t0 = blockIdx.y * 128;
    const __bf16* qb = qT + ((size_t)bh << 16);
    const __bf16* kb = kT + ((size_t)bh << 16);
    const __bf16* vb = vv + ((size_t)bh << 6) * NHW;
    const int xmask = l15 & 14;

    // per-lane V staging source offset (within a 64-s tile), for inst' = (w-2)*4+i
    // lane covers c = inst'*8 + (lane>>3), 16B chunk m = lane&7,
    // source s-chunk pair start = 4 * ((2m) ^ (c & 14))
    // Q fragments in registers: B[n=t][k=c] layout, t = t0+w*32+tb*16+l15
    bf16x8 qfr[2][2];
    #pragma unroll
    for (int tb = 0; tb < 2; tb++)
        #pragma unroll
        for (int ch = 0; ch < 2; ch++)
            qfr[tb][ch] = *(const bf16x8*)(qb + (size_t)(t0 + w * 32 + tb * 16 + l15) * 64
                                           + ch * 32 + quad * 8);
    // stage K/V tile 0 into buffer 0
    #pragma unroll
    for (int i = 0; i < 4; i++) {
        int inst = w * 4 + i;
        if (inst < 8) {
            int ch = inst >> 2, sb = (inst & 3) * 16;
            gload_lds16(kb + (size_t)(sb + lr) * 64 + ch * 32 + lk,
                        Kt + ch * 2048 + sb * 32);
        } else {
            int ip = inst - 8;
            int c = ip * 8 + (lane >> 3);
            int m2 = (lane & 7) * 2;
            gload_lds16(vb + (size_t)c * NHW + 4 * (m2 ^ (c & 14)),
                        Vt + ip * 512);
        }
    }
    float lp[2] = {0.f, 0.f};
    f32x4 Oacc[2][4] = {};

    for (int it = 0; it < 16; it++) {
        const int cur = (it & 1) * 4096;
        const int nxt = 4096 - cur;
        dma_drain();
        __syncthreads();
        if (it + 1 < 16) {
            const int s0 = (it + 1) * 64;
            #pragma unroll
            for (int i = 0; i < 4; i++) {
                int inst = w * 4 + i;
                if (inst < 8) {
                    int ch = inst >> 2, sb = (inst & 3) * 16;
                    gload_lds16(kb + (size_t)(s0 + sb + lr) * 64 + ch * 32 + lk,
                                Kt + nxt + ch * 2048 + sb * 32);
                } else {
                    int ip = inst - 8;
                    int c = ip * 8 + (lane >> 3);
                    int m2 = (lane & 7) * 2;
                    gload_lds16(vb + (size_t)c * NHW + s0 + 4 * (m2 ^ (c & 14)),
                                Vt + nxt + ip * 512);
                }
            }
        }
        // S^T tiles: sacc[tb][j] covers s in [16j,16j+16), t-block tb
        f32x4 sacc[2][4] = {};
        #pragma unroll
        for (int ch = 0; ch < 2; ch++)
            #pragma unroll
            for (int j = 0; j < 4; j++) {
                bf16x8 kfr = *(const bf16x8*)(Kt + cur + ch * 2048
                                              + (j * 16 + l15) * 32 + quad * 8);
                sacc[0][j] = __builtin_amdgcn_mfma_f32_16x16x32_bf16(
                    kfr, qfr[0][ch], sacc[0][j], 0, 0, 0);
                sacc[1][j] = __builtin_amdgcn_mfma_f32_16x16x32_bf16(
                    kfr, qfr[1][ch], sacc[1][j], 0, 0, 0);
            }
        // P = exp2(S^T) in registers; pack to A-frags for K=16 PV mfma
        bf16x4 pf[2][4];
        #pragma unroll
        for (int tb = 0; tb < 2; tb++)
            #pragma unroll
            for (int j = 0; j < 4; j++) {
                bf16x4 pk;
                #pragma unroll
                for (int r = 0; r < 4; r++) {
                    float pv = __builtin_amdgcn_exp2f(sacc[tb][j][r]);
                    lp[tb] += pv;
                    pk[r] = (__bf16)pv;
                }
                pf[tb][j] = pk;
            }
        // O^T[t][c] += P[t][s] * V[c][s]; V read via XOR-swizzled b64 (conflict-free)
        #pragma unroll
        for (int jt = 0; jt < 4; jt++) {
            const __bf16* vbase = Vt + cur + (((jt * 4 + quad) ^ xmask) << 2);
            #pragma unroll
            for (int ci = 0; ci < 4; ci++) {
                bf16x4 vfr = *(const bf16x4*)(vbase + (ci * 16 + l15) * 64);
                Oacc[0][ci] = mfma16(pf[0][jt], vfr, Oacc[0][ci]);
                Oacc[1][ci] = mfma16(pf[1][jt], vfr, Oacc[1][ci]);
            }
        }
    }
    const int b = bh >> 3, hh = bh & 7;
    #pragma unroll
    for (int tb = 0; tb < 2; tb++) {
        float s = lp[tb];
        s += __shfl_xor(s, 16);
        s += __shfl_xor(s, 32);     // every lane: row-sum for t_local = l15
        #pragma unroll
        for (int r = 0; r < 4; r++) {
            float inv = 1.f / __shfl(s, quad * 4 + r);
            int t = t0 + w * 32 + tb * 16 + quad * 4 + r;
            size_t base = ((size_t)(b * NHW + t)) * NC + hh * 64;
            #pragma unroll
            for (int ci = 0; ci < 4; ci++)
                aT[base + ci * 16 + l15] = (__bf16)(Oacc[tb][ci][r] * inv);
        }
    }
}

// ---------------- final: out = x + GN2(projb), stats from gstat sums ----------------
__global__ __launch_bounds__(256) void final_k(const float* __restrict__ x,
                                               const __bf16* __restrict__ pb,
                                               const float* __restrict__ gstat,
                                               const float* __restrict__ sc,
                                               const float* __restrict__ bi,
                                               float* __restrict__ out) {
    const int i4 = blockIdx.x * 256 + threadIdx.x;
    const int c  = (i4 >> 8) & (NC - 1);
    const int b  = i4 >> 17;
    const int grp = b * NG + (c >> 4);
    const float inv = 1.f / (float)(CPG * NHW);
    const float m = gstat[grp] * inv;
    const float var = gstat[256 + grp] * inv - m * m;
    const float r = rsqrtf(var + EPS);
    const float a = sc[c] * r;
    const float d = bi[c] - m * a;
    float4 xv = ((const float4*)x)[i4];
    bf16x4 pv = ((const bf16x4*)pb)[i4];
    float4 o = make_float4(xv.x + (float)pv[0] * a + d, xv.y + (float)pv[1] * a + d,
                           xv.z + (float)pv[2] * a + d, xv.w + (float)pv[3] * a + d);
    ((float4*)out)[i4] = o;
}

extern "C" void kernel_launch(void* const* d_in, const int* in_sizes, int n_in,
                              void* d_out, int out_size, void* d_ws, size_t ws_size,
                              hipStream_t stream) {
    const float* x      = (const float*)d_in[0];
    const float* gn1_s  = (const float*)d_in[1];
    const float* gn1_b  = (const float*)d_in[2];
    const float* w_qkv  = (const float*)d_in[3];
    const float* b_qkv  = (const float*)d_in[4];
    const float* w_proj = (const float*)d_in[5];
    const float* b_proj = (const float*)d_in[6];
    const float* gn2_s  = (const float*)d_in[7];
    const float* gn2_b  = (const float*)d_in[8];
    float* out = (float*)d_out;

    char* p = (char*)d_ws;
    __bf16* hnT   = (__bf16*)p;           p += (size_t)8 * 1024 * 512 * 2;   // 8 MB
    __bf16* qT    = (__bf16*)p;           p += (size_t)64 * 1024 * 64 * 2;   // 8 MB
    __bf16* kT    = (__bf16*)p;           p += (size_t)64 * 1024 * 64 * 2;   // 8 MB
    __bf16* vB    = (__bf16*)p;           p += (size_t)64 * 64 * 1024 * 2;   // 8 MB
    __bf16* aT    = (__bf16*)p;           p += (size_t)8 * 1024 * 512 * 2;   // 8 MB
    __bf16* projb = (__bf16*)p;           p += (size_t)8 * 512 * 1024 * 2;   // 8 MB
    __bf16* wq    = (__bf16*)p;           p += (size_t)QKV_C * NC * 2;       // 1.5 MB
    __bf16* wp    = (__bf16*)p;           p += (size_t)NC * NC * 2;          // 0.5 MB
    float*  mu1   = (float*)p;            p += 256 * 4;
    float*  ri1   = (float*)p;            p += 256 * 4;
    float*  gstat = (float*)p;            p += 512 * 4;   // [0:256) sum, [256:512) sumsq

    // blocks: 256 stats + 1024 cvt
    prep_k<<<1280, 256, 0, stream>>>(x, mu1, ri1, w_qkv, wq, w_proj, wp, gstat);
    gn_apply_t_k<<<dim3(16, 8, 8), 256, 0, stream>>>(x, mu1, ri1, gn1_s, gn1_b, hnT);

    qkv_gemm_k<<<dim3(12, 8, 8), 256, 0, stream>>>(wq, hnT, b_qkv, qT, kT, vB);

    attn_k<<<dim3(64, 8), 256, 0, stream>>>(qT, kT, vB, aT);

    proj_gemm_k<<<dim3(4, 8, 8), 256, 0, stream>>>(wp, aT, b_proj, projb, gstat);

    final_k<<<4096, 256, 0, stream>>>(x, projb, gstat, gn2_s, gn2_b, out);
}